// Round 2
// baseline (3126.466 us; speedup 1.0000x reference)
//
#include <hip/hip_runtime.h>
#include <cmath>

// ---------------- problem constants ----------------
constexpr int BB = 4;              // batch
constexpr int SS = 1024;           // seq len
constexpr int DD = 512;            // model dim
constexpr int MM = 64;             // meta tokens
constexpr int TT = MM + SS;        // 1088
constexpr int HH = 8;              // heads
constexpr int HD = DD / HH;        // 64
constexpr int WINDOW = 128;
constexpr int RROWS = BB * TT;     // 4352 token rows
constexpr int OROWS = BB * SS;     // 4096 output rows
constexpr float LR_ = 1e-3f;
constexpr float WD_ = 1e-2f;
constexpr float MAXALR_ = 0.1f;
constexpr float EPS_ = 1e-8f;

static_assert(RROWS % 32 == 0 && DD % 32 == 0 && OROWS % 32 == 0, "tile divisibility");

// ---------------- elementwise kernels ----------------
__global__ void build_xm_k(const float* __restrict__ x, const float* __restrict__ meta,
                           float* __restrict__ xm) {
    size_t idx = (size_t)blockIdx.x * 256 + threadIdx.x;
    if (idx >= (size_t)BB * TT * DD) return;
    int d = (int)(idx % DD);
    int t = (int)((idx / DD) % TT);
    int b = (int)(idx / ((size_t)DD * TT));
    xm[idx] = (t < MM) ? meta[t * DD + d]
                       : x[((size_t)b * SS + (t - MM)) * DD + d];
}

// hout = hin + silu(z)
__global__ void addsilu_k(const float* __restrict__ hin, const float* __restrict__ z,
                          float* __restrict__ hout, size_t n) {
    size_t i = (size_t)blockIdx.x * 256 + threadIdx.x;
    if (i >= n) return;
    float zz = z[i];
    float s = 1.f / (1.f + expf(-zz));
    hout[i] = hin[i] + zz * s;
}

// P <- (2/D) * w[row] * (P - v)   (dLoss/dpreds)
__global__ void d2_k(float* __restrict__ P, const float* __restrict__ v,
                     const float* __restrict__ w, size_t n) {
    size_t i = (size_t)blockIdx.x * 256 + threadIdx.x;
    if (i >= n) return;
    size_t row = i / DD;
    P[i] = (2.f / (float)DD) * w[row] * (P[i] - v[i]);
}

// out = dh * silu'(z);  silu'(z) = sig(z)*(1 + z*(1-sig(z)))
__global__ void dsilu_k(const float* __restrict__ dh, const float* __restrict__ z,
                        float* __restrict__ out, size_t n) {
    size_t i = (size_t)blockIdx.x * 256 + threadIdx.x;
    if (i >= n) return;
    float zz = z[i];
    float s = 1.f / (1.f + expf(-zz));
    out[i] = dh[i] * (s * (1.f + zz * (1.f - s)));
}

// out = p*(1-lr*wd) - lr * g/(|g|+eps)
__global__ void adamw_k(const float* __restrict__ p, const float* __restrict__ g,
                        float* __restrict__ out, size_t n) {
    size_t i = (size_t)blockIdx.x * 256 + threadIdx.x;
    if (i >= n) return;
    float gg = g[i];
    out[i] = p[i] * (1.f - LR_ * WD_) - LR_ * gg / (fabsf(gg) + EPS_);
}

// w[row] = sigmoid(dot(xm[row], Wlr) + blr) * MAX_ALR     (one wave per row)
__global__ void lr_k(const float* __restrict__ xm, const float* __restrict__ Wlr,
                     const float* __restrict__ blr, float* __restrict__ w) {
    int gid = blockIdx.x * 256 + threadIdx.x;
    int row = gid >> 6;
    int lane = gid & 63;
    if (row >= RROWS) return;
    const float* xr = xm + (size_t)row * DD;
    float s = 0.f;
    for (int d = lane; d < DD; d += 64) s += xr[d] * Wlr[d];
    for (int off = 32; off; off >>= 1) s += __shfl_down(s, off);
    if (lane == 0) w[row] = MAXALR_ / (1.f + expf(-(s + blr[0])));
}

// column sums: out[c] = sum_r X[r*N + c];  grid.x = N/64, block = 256 (64 cols x 4 row groups)
__global__ void colsum_k(const float* __restrict__ X, float* __restrict__ out, int R, int N) {
    int c = blockIdx.x * 64 + (threadIdx.x & 63);
    int rg = threadIdx.x >> 6;
    float s = 0.f;
    for (int r = rg; r < R; r += 4) s += X[(size_t)r * N + c];
    __shared__ float sm[256];
    sm[threadIdx.x] = s;
    __syncthreads();
    if (rg == 0) out[c] = sm[threadIdx.x] + sm[threadIdx.x + 64] + sm[threadIdx.x + 128] + sm[threadIdx.x + 192];
}

// ---------------- generic tiled fp32 GEMM ----------------
// C[Mr,N] = opA(A)[Mr,K] @ opB(B)[K,N] (+ bias[n]) (+ Cin[m,n])
// TA: A stored [K,Mr] row-major.  TB: B stored [N,K] row-major.
template<bool TA, bool TB, bool ADDC>
__global__ __launch_bounds__(1024) void gemm_kernel(
    const float* __restrict__ A, const float* __restrict__ B,
    const float* __restrict__ bias, const float* __restrict__ Cin,
    float* __restrict__ C, int Mr, int N, int K) {
    __shared__ float As[32][33];
    __shared__ float Bs[32][33];
    int tx = threadIdx.x;           // n / k
    int ty = threadIdx.y;           // m / k
    int n0 = blockIdx.x * 32;
    int m0 = blockIdx.y * 32;
    int m = m0 + ty, n = n0 + tx;
    float acc = 0.f;
    for (int k0 = 0; k0 < K; k0 += 32) {
        int am = m0 + ty, ak = k0 + tx;
        As[ty][tx] = TA ? A[(size_t)ak * Mr + am] : A[(size_t)am * K + ak];
        int bk = k0 + ty, bn = n0 + tx;
        Bs[ty][tx] = TB ? B[(size_t)bn * K + bk] : B[(size_t)bk * N + bn];
        __syncthreads();
#pragma unroll
        for (int kk = 0; kk < 32; ++kk)
            acc += As[ty][kk] * Bs[kk][tx];
        __syncthreads();
    }
    float r = acc;
    if (bias) r += bias[n];
    if (ADDC) r += Cin[(size_t)m * N + n];
    C[(size_t)m * N + n] = r;
}

// ---------------- sliding window attention ----------------
// one block per (b, h, output row i = M + s); block = 128 threads
__global__ __launch_bounds__(128) void swa_k(const float* __restrict__ Q,
                                             const float* __restrict__ K,
                                             const float* __restrict__ V,
                                             float* __restrict__ O) {
    int bid = blockIdx.x;
    int s = bid % SS;
    int h = (bid / SS) % HH;
    int b = bid / (SS * HH);
    int i = MM + s;
    int jlo = i - WINDOW + 1; if (jlo < 0) jlo = 0;
    int cnt = i - jlo + 1;                 // <= 128
    int tid = threadIdx.x;

    __shared__ float qs[HD];
    __shared__ float sc[128];
    __shared__ float red[128];

    if (tid < HD) qs[tid] = Q[((size_t)b * TT + i) * DD + h * HD + tid];
    __syncthreads();

    float score = -1e30f;
    if (tid < cnt) {
        const float* kr = K + ((size_t)b * TT + jlo + tid) * DD + h * HD;
        float sd = 0.f;
#pragma unroll
        for (int d = 0; d < HD; ++d) sd += qs[d] * kr[d];
        score = sd * 0.125f;               // 1/sqrt(64)
    }
    sc[tid] = score;
    red[tid] = score;
    __syncthreads();
    for (int off = 64; off; off >>= 1) {
        if (tid < off) red[tid] = fmaxf(red[tid], red[tid + off]);
        __syncthreads();
    }
    float mx = red[0];
    __syncthreads();
    float e = (tid < cnt) ? expf(sc[tid] - mx) : 0.f;
    sc[tid] = e;
    red[tid] = e;
    __syncthreads();
    for (int off = 64; off; off >>= 1) {
        if (tid < off) red[tid] += red[tid + off];
        __syncthreads();
    }
    float inv = 1.f / red[0];
    __syncthreads();

    if (tid < HD) {
        const float* vb = V + ((size_t)b * TT + jlo) * DD + h * HD + tid;
        float o = 0.f;
        for (int j = 0; j < cnt; ++j) o += sc[j] * vb[(size_t)j * DD];
        O[((size_t)b * SS + s) * DD + h * HD + tid] = o * inv;
    }
}

// ---------------- launch ----------------
extern "C" void kernel_launch(void* const* d_in, const int* in_sizes, int n_in,
                              void* d_out, int out_size, void* d_ws, size_t ws_size,
                              hipStream_t stream) {
    const float* x    = (const float*)d_in[0];
    const float* meta = (const float*)d_in[1];
    const float* lmmW = (const float*)d_in[2];
    const float* lmmb = (const float*)d_in[3];
    const float* Wq   = (const float*)d_in[4];
    const float* bq   = (const float*)d_in[5];
    const float* Wk   = (const float*)d_in[6];
    const float* bk   = (const float*)d_in[7];
    const float* Wv   = (const float*)d_in[8];
    const float* bv   = (const float*)d_in[9];
    const float* Wlr  = (const float*)d_in[10];
    const float* blr  = (const float*)d_in[11];
    const float* swaW = (const float*)d_in[12];
    const float* swab = (const float*)d_in[13];
    float* out = (float*)d_out;
    (void)in_sizes; (void)n_in; (void)out_size; (void)ws_size;

    float* base = (float*)d_ws;
    size_t off = 0;
    auto alloc = [&](size_t n) { float* p = base + off; off += (n + 63) & ~(size_t)63; return p; };
    const size_t BIG = (size_t)RROWS * DD;        // 2,228,224 floats
    float* xm  = alloc(BIG);   // later reused as av
    float* q   = alloc(BIG);
    float* k   = alloc(BIG);   // later ak
    float* v   = alloc(BIG);   // later aq
    float* z1  = alloc(BIG);   // later dz1 (in place), then retrieval z1
    float* h1  = alloc(BIG);
    float* z2  = alloc(BIG);
    float* P   = alloc(BIG);   // preds -> d2 -> dh1 -> retrieved
    float* dz2 = alloc(BIG);
    float* o   = alloc((size_t)OROWS * DD);
    float* w   = alloc(RROWS);
    float* gW  = alloc(2 * DD * DD);
    float* gb  = alloc(2 * DD);
    float* Wn  = alloc(2 * DD * DD);
    float* bn  = alloc(2 * DD);

    dim3 gblk(32, 32);
    auto gemm_nn = [&](const float* A, const float* Bm, const float* bias, float* C,
                       int Mr, int N, int K) {
        dim3 grid(N / 32, Mr / 32);
        gemm_kernel<false, false, false><<<grid, gblk, 0, stream>>>(A, Bm, bias, nullptr, C, Mr, N, K);
    };
    auto gemm_tn = [&](const float* A, const float* Bm, float* C, int Mr, int N, int K) {
        dim3 grid(N / 32, Mr / 32);
        gemm_kernel<true, false, false><<<grid, gblk, 0, stream>>>(A, Bm, nullptr, nullptr, C, Mr, N, K);
    };
    auto gemm_nt_add = [&](const float* A, const float* Bm, const float* Cin, float* C,
                           int Mr, int N, int K) {
        dim3 grid(N / 32, Mr / 32);
        gemm_kernel<false, true, true><<<grid, gblk, 0, stream>>>(A, Bm, nullptr, Cin, C, Mr, N, K);
    };

    int ewb = (int)((BIG + 255) / 256);

    // 1) xm = concat(meta, x)
    build_xm_k<<<ewb, 256, 0, stream>>>(x, meta, xm);

    // 2) projections + adaptive lr
    gemm_nn(xm, Wq, bq, q, RROWS, DD, DD);
    gemm_nn(xm, Wk, bk, k, RROWS, DD, DD);
    gemm_nn(xm, Wv, bv, v, RROWS, DD, DD);
    lr_k<<<(RROWS * 64 + 255) / 256, 256, 0, stream>>>(xm, Wlr, blr, w);

    // 3) lmm forward on k (store z1, h1, z2, preds->P)
    gemm_nn(k, lmmW, lmmb, z1, RROWS, DD, DD);
    addsilu_k<<<ewb, 256, 0, stream>>>(k, z1, h1, BIG);
    gemm_nn(h1, lmmW + DD * DD, lmmb + DD, z2, RROWS, DD, DD);
    addsilu_k<<<ewb, 256, 0, stream>>>(h1, z2, P, BIG);

    // 4) backward
    d2_k<<<ewb, 256, 0, stream>>>(P, v, w, BIG);                  // P = d2
    dsilu_k<<<ewb, 256, 0, stream>>>(P, z2, dz2, BIG);            // dz2
    gemm_tn(h1, dz2, gW + DD * DD, DD, DD, RROWS);                // gW1 = h1^T dz2
    colsum_k<<<DD / 64, 256, 0, stream>>>(dz2, gb + DD, RROWS, DD);
    gemm_nt_add(dz2, lmmW + DD * DD, P, P, RROWS, DD, DD);        // P = dh1 = d2 + dz2 W1^T
    dsilu_k<<<ewb, 256, 0, stream>>>(P, z1, z1, BIG);             // z1 = dz1
    gemm_tn(k, z1, gW, DD, DD, RROWS);                            // gW0 = k^T dz1
    colsum_k<<<DD / 64, 256, 0, stream>>>(z1, gb, RROWS, DD);

    // 5) AdamW-style update
    adamw_k<<<(2 * DD * DD + 255) / 256, 256, 0, stream>>>(lmmW, gW, Wn, (size_t)2 * DD * DD);
    adamw_k<<<(2 * DD + 255) / 256, 256, 0, stream>>>(lmmb, gb, bn, (size_t)2 * DD);

    // 6) retrieval with updated memory
    gemm_nn(q, Wn, bn, z1, RROWS, DD, DD);
    addsilu_k<<<ewb, 256, 0, stream>>>(q, z1, h1, BIG);
    gemm_nn(h1, Wn + DD * DD, bn + DD, z2, RROWS, DD, DD);
    addsilu_k<<<ewb, 256, 0, stream>>>(h1, z2, P, BIG);           // P = retrieved

    // 7) sliding-window attention
    gemm_nn(P, swaW + 0 * DD * DD, swab + 0 * DD, v, RROWS, DD, DD);   // aq
    gemm_nn(P, swaW + 1 * DD * DD, swab + 1 * DD, k, RROWS, DD, DD);   // ak
    gemm_nn(P, swaW + 2 * DD * DD, swab + 2 * DD, xm, RROWS, DD, DD);  // av
    swa_k<<<BB * HH * SS, 128, 0, stream>>>(v, k, xm, o);
    gemm_nn(o, swaW + 3 * DD * DD, swab + 3 * DD, out, OROWS, DD, DD); // final proj
}

// Round 3
// 498.698 us; speedup vs baseline: 6.2693x; 6.2693x over previous
//
#include <hip/hip_runtime.h>
#include <cmath>

// ---------------- problem constants ----------------
constexpr int BB = 4, SSQ = 1024, DD = 512, MM = 64, TTK = MM + SSQ; // 1088
constexpr int HH = 8, HD = DD / HH, WINDOW = 128;
constexpr int RROWS = BB * TTK;     // 4352
constexpr int OROWS = BB * SSQ;     // 4096
constexpr float LR_ = 1e-3f, WD_ = 1e-2f, MAXALR_ = 0.1f, EPS_ = 1e-8f;
constexpr float C2_ = 2.0f / (float)DD;

typedef short  s16x8 __attribute__((ext_vector_type(8)));
typedef float  f32x4 __attribute__((ext_vector_type(4)));

__device__ __forceinline__ float b2f(unsigned short u) {
    union { unsigned int i; float f; } c; c.i = ((unsigned int)u) << 16; return c.f;
}
__device__ __forceinline__ unsigned short f2b(float f) {
    union { float f; unsigned int i; } c; c.f = f;
    unsigned int r = c.i + 0x7fffu + ((c.i >> 16) & 1u);   // RNE
    return (unsigned short)(r >> 16);
}
__device__ __forceinline__ float sigm(float x) { return 1.f / (1.f + __expf(-x)); }

__device__ __forceinline__ void gld16(const void* g, void* l) {
    __builtin_amdgcn_global_load_lds((const __attribute__((address_space(1))) unsigned int*)g,
                                     (__attribute__((address_space(3))) unsigned int*)l, 16, 0, 0);
}

// ---------------- canonical bf16 MFMA GEMM ----------------
// C[M,N] = sum_k A[m][k]*B[n][k]  (+bias[n])  -- A:[M,K] k-contig, B:[N,K] k-contig
// EPI: 0 bf16-out | 1 add-silu (h=base+silu(z)) | 2 add-silu + write z
//      3 pred/d2/dz2 fused | 4 dh1/dz1 fused | 5 f32-out | 6 f32 atomicAdd (split-K)
template<int EPI>
__global__ __launch_bounds__(256) void mgemm(
    const unsigned short* __restrict__ A, const unsigned short* __restrict__ Bm,
    const float* __restrict__ bias,
    const unsigned short* __restrict__ aux0, const unsigned short* __restrict__ aux1,
    const float* __restrict__ wrow,
    void* __restrict__ out0, unsigned short* __restrict__ out1,
    int M, int N, int K)
{
    __shared__ unsigned short As[128 * 32];
    __shared__ unsigned short Bs[128 * 32];
    const int tid = threadIdx.x;
    const int m0 = blockIdx.y * 128, n0 = blockIdx.x * 128;
    const int ktiles = K >> 5;
    const int per = ktiles / gridDim.z;
    const int kt0 = blockIdx.z * per, kt1 = kt0 + per;

    const int sm = tid >> 2, sc = tid & 3;           // staging row / 16B chunk
    const unsigned short* Ag = A + (size_t)(m0 + sm) * K + sc * 8;
    const unsigned short* Bg = Bm + (size_t)(n0 + sm) * K + sc * 8;

    f32x4 acc[4][4];
#pragma unroll
    for (int i = 0; i < 4; ++i)
#pragma unroll
        for (int j = 0; j < 4; ++j)
#pragma unroll
            for (int r = 0; r < 4; ++r) acc[i][j][r] = 0.f;

    const int lane = tid & 63, wv = tid >> 6;
    const int wr = wv >> 1, wc = wv & 1;             // 2x2 wave grid, 64x64 each
    const int fr = lane & 15, fg = lane >> 4;        // frag row/col + k-group

    for (int kt = kt0; kt < kt1; ++kt) {
        const int kb = kt << 5;
        gld16(Ag + kb,                 &As[tid * 8]);
        gld16(Ag + (size_t)64 * K + kb, &As[64 * 32 + tid * 8]);
        gld16(Bg + kb,                 &Bs[tid * 8]);
        gld16(Bg + (size_t)64 * K + kb, &Bs[64 * 32 + tid * 8]);
        __syncthreads();
        s16x8 a[4], b[4];
#pragma unroll
        for (int i = 0; i < 4; ++i) a[i] = *(const s16x8*)&As[(wr * 64 + i * 16 + fr) * 32 + fg * 8];
#pragma unroll
        for (int j = 0; j < 4; ++j) b[j] = *(const s16x8*)&Bs[(wc * 64 + j * 16 + fr) * 32 + fg * 8];
#pragma unroll
        for (int i = 0; i < 4; ++i)
#pragma unroll
            for (int j = 0; j < 4; ++j)
                acc[i][j] = __builtin_amdgcn_mfma_f32_16x16x32_bf16(a[i], b[j], acc[i][j], 0, 0, 0);
        __syncthreads();
    }

    // epilogue: C/D layout col=lane&15, row=(lane>>4)*4+reg  [m89-verified]
#pragma unroll
    for (int j = 0; j < 4; ++j) {
        const int col = n0 + wc * 64 + j * 16 + fr;
        const float bj = (EPI == 6 || bias == nullptr) ? 0.f : bias[col];
#pragma unroll
        for (int i = 0; i < 4; ++i) {
            const int rowb = m0 + wr * 64 + i * 16 + fg * 4;
#pragma unroll
            for (int r = 0; r < 4; ++r) {
                const int row = rowb + r;
                const size_t off = (size_t)row * N + col;
                float val = acc[i][j][r] + bj;
                if (EPI == 0) {
                    ((unsigned short*)out0)[off] = f2b(val);
                } else if (EPI == 1 || EPI == 2) {
                    float base = b2f(aux0[off]);
                    float h = base + val * sigm(val);
                    ((unsigned short*)out0)[off] = f2b(h);
                    if (EPI == 2) out1[off] = f2b(val);
                } else if (EPI == 3) {
                    float h1 = b2f(aux0[off]);
                    float pred = h1 + val * sigm(val);
                    float vv = b2f(aux1[off]);
                    float d2 = C2_ * wrow[row] * (pred - vv);
                    float s = sigm(val);
                    float dz2 = d2 * (s * (1.f + val * (1.f - s)));
                    ((unsigned short*)out0)[off] = f2b(d2);
                    out1[off] = f2b(dz2);
                } else if (EPI == 4) {
                    float dh = val + b2f(aux0[off]);
                    float z1 = b2f(aux1[off]);
                    float s = sigm(z1);
                    ((unsigned short*)out0)[off] = f2b(dh * (s * (1.f + z1 * (1.f - s))));
                } else if (EPI == 5) {
                    ((float*)out0)[off] = val;
                } else {
                    atomicAdd((float*)out0 + off, val);
                }
            }
        }
    }
}

// ---------------- transposes ----------------
__global__ __launch_bounds__(256) void transp_b2b(const unsigned short* __restrict__ src,
                                                  unsigned short* __restrict__ dst, int R, int C) {
    __shared__ unsigned short t[64][65];
    int r0 = blockIdx.y * 64, c0 = blockIdx.x * 64;
    int lr = threadIdx.x >> 4, lc = (threadIdx.x & 15) * 4;
#pragma unroll
    for (int rr = 0; rr < 64; rr += 16) {
        ushort4 v = *(const ushort4*)(src + (size_t)(r0 + lr + rr) * C + c0 + lc);
        t[lr + rr][lc] = v.x; t[lr + rr][lc + 1] = v.y; t[lr + rr][lc + 2] = v.z; t[lr + rr][lc + 3] = v.w;
    }
    __syncthreads();
#pragma unroll
    for (int cc = 0; cc < 64; cc += 16) {
        int c = lr + cc;
        ushort4 o; o.x = t[lc][c]; o.y = t[lc + 1][c]; o.z = t[lc + 2][c]; o.w = t[lc + 3][c];
        *(ushort4*)(dst + (size_t)(c0 + c) * R + r0 + lc) = o;
    }
}

struct TXP { const float* s[12]; unsigned short* d[12]; };
__global__ __launch_bounds__(256) void transp_f2b(TXP p) {   // 512x512 fp32 -> bf16 transposed
    const float* src = p.s[blockIdx.z];
    unsigned short* dst = p.d[blockIdx.z];
    __shared__ unsigned short t[64][65];
    int r0 = blockIdx.y * 64, c0 = blockIdx.x * 64;
    int lr = threadIdx.x >> 4, lc = (threadIdx.x & 15) * 4;
#pragma unroll
    for (int rr = 0; rr < 64; rr += 16) {
        float4 v = *(const float4*)(src + (size_t)(r0 + lr + rr) * 512 + c0 + lc);
        t[lr + rr][lc] = f2b(v.x); t[lr + rr][lc + 1] = f2b(v.y);
        t[lr + rr][lc + 2] = f2b(v.z); t[lr + rr][lc + 3] = f2b(v.w);
    }
    __syncthreads();
#pragma unroll
    for (int cc = 0; cc < 64; cc += 16) {
        int c = lr + cc;
        ushort4 o; o.x = t[lc][c]; o.y = t[lc + 1][c]; o.z = t[lc + 2][c]; o.w = t[lc + 3][c];
        *(ushort4*)(dst + (size_t)(c0 + c) * 512 + r0 + lc) = o;
    }
}

__global__ void convf2b_k(const float* __restrict__ s, unsigned short* __restrict__ d, int n) {
    int i = blockIdx.x * 256 + threadIdx.x;
    if (i < n) d[i] = f2b(s[i]);
}

// ---------------- small kernels ----------------
__global__ void build_xm_k(const float* __restrict__ x, const float* __restrict__ meta,
                           unsigned short* __restrict__ xm) {
    size_t idx = (size_t)blockIdx.x * 256 + threadIdx.x;
    if (idx >= (size_t)RROWS * DD) return;
    int d = (int)(idx % DD);
    int t = (int)((idx / DD) % TTK);
    int b = (int)(idx / ((size_t)DD * TTK));
    float v = (t < MM) ? meta[t * DD + d] : x[((size_t)b * SSQ + (t - MM)) * DD + d];
    xm[idx] = f2b(v);
}

__global__ void adamw_k(const float* __restrict__ p, const float* __restrict__ g,
                        float* __restrict__ out, int n) {
    int i = blockIdx.x * 256 + threadIdx.x;
    if (i >= n) return;
    float gg = g[i];
    out[i] = p[i] * (1.f - LR_ * WD_) - LR_ * gg / (fabsf(gg) + EPS_);
}

__global__ void lr_k(const unsigned short* __restrict__ xm, const float* __restrict__ Wlr,
                     const float* __restrict__ blr, float* __restrict__ w) {
    int gid = blockIdx.x * 256 + threadIdx.x;
    int row = gid >> 6, lane = gid & 63;
    if (row >= RROWS) return;
    const unsigned short* xr = xm + (size_t)row * DD;
    float s = 0.f;
    for (int d = lane; d < DD; d += 64) s += b2f(xr[d]) * Wlr[d];
    for (int off = 32; off; off >>= 1) s += __shfl_down(s, off);
    if (lane == 0) w[row] = MAXALR_ / (1.f + __expf(-(s + blr[0])));
}

__global__ __launch_bounds__(256) void rowsum_k(const unsigned short* __restrict__ src,
                                                float* __restrict__ dst, int C) {
    int row = blockIdx.x;
    const unsigned short* p = src + (size_t)row * C;
    float s = 0.f;
    for (int c = threadIdx.x; c < C; c += 256) s += b2f(p[c]);
    for (int off = 32; off; off >>= 1) s += __shfl_down(s, off);
    __shared__ float sm[4];
    if ((threadIdx.x & 63) == 0) sm[threadIdx.x >> 6] = s;
    __syncthreads();
    if (threadIdx.x == 0) dst[row] = sm[0] + sm[1] + sm[2] + sm[3];
}

__global__ void zero_k(float* p, int n) {
    int i = blockIdx.x * 256 + threadIdx.x;
    if (i < n) p[i] = 0.f;
}

// ---------------- sliding window attention (bf16 in/out) ----------------
__global__ __launch_bounds__(128) void swa_k(const unsigned short* __restrict__ Q,
                                             const unsigned short* __restrict__ K,
                                             const unsigned short* __restrict__ V,
                                             unsigned short* __restrict__ O) {
    int bid = blockIdx.x;
    int s = bid % SSQ;
    int h = (bid / SSQ) % HH;
    int b = bid / (SSQ * HH);
    int i = MM + s;
    int jlo = i - WINDOW + 1; if (jlo < 0) jlo = 0;
    int cnt = i - jlo + 1;
    int tid = threadIdx.x;

    __shared__ float qs[HD];
    __shared__ float scs[WINDOW];
    __shared__ float red[WINDOW];

    if (tid < HD) qs[tid] = b2f(Q[((size_t)b * TTK + i) * DD + h * HD + tid]);
    __syncthreads();

    float score = -1e30f;
    if (tid < cnt) {
        const ushort4* kr = (const ushort4*)(K + ((size_t)b * TTK + jlo + tid) * DD + h * HD);
        float sd = 0.f;
#pragma unroll
        for (int d4 = 0; d4 < HD / 4; ++d4) {
            ushort4 kv = kr[d4];
            sd += qs[d4 * 4 + 0] * b2f(kv.x) + qs[d4 * 4 + 1] * b2f(kv.y)
                + qs[d4 * 4 + 2] * b2f(kv.z) + qs[d4 * 4 + 3] * b2f(kv.w);
        }
        score = sd * 0.125f;
    }
    scs[tid] = score; red[tid] = score;
    __syncthreads();
    for (int off = 64; off; off >>= 1) {
        if (tid < off) red[tid] = fmaxf(red[tid], red[tid + off]);
        __syncthreads();
    }
    float mx = red[0];
    __syncthreads();
    float e = (tid < cnt) ? __expf(scs[tid] - mx) : 0.f;
    scs[tid] = e; red[tid] = e;
    __syncthreads();
    for (int off = 64; off; off >>= 1) {
        if (tid < off) red[tid] += red[tid + off];
        __syncthreads();
    }
    float inv = 1.f / red[0];
    __syncthreads();

    if (tid < HD) {
        const unsigned short* vb = V + ((size_t)b * TTK + jlo) * DD + h * HD + tid;
        float o = 0.f;
        for (int j = 0; j < cnt; ++j) o += scs[j] * b2f(vb[(size_t)j * DD]);
        O[((size_t)b * SSQ + s) * DD + h * HD + tid] = f2b(o * inv);
    }
}

// ---------------- launch ----------------
extern "C" void kernel_launch(void* const* d_in, const int* in_sizes, int n_in,
                              void* d_out, int out_size, void* d_ws, size_t ws_size,
                              hipStream_t stream) {
    const float* x    = (const float*)d_in[0];
    const float* meta = (const float*)d_in[1];
    const float* lmmW = (const float*)d_in[2];
    const float* lmmb = (const float*)d_in[3];
    const float* Wq   = (const float*)d_in[4];
    const float* bq   = (const float*)d_in[5];
    const float* Wk   = (const float*)d_in[6];
    const float* bk   = (const float*)d_in[7];
    const float* Wv   = (const float*)d_in[8];
    const float* bv   = (const float*)d_in[9];
    const float* Wlr  = (const float*)d_in[10];
    const float* blr  = (const float*)d_in[11];
    const float* swaW = (const float*)d_in[12];
    const float* swab = (const float*)d_in[13];
    float* out = (float*)d_out;
    (void)in_sizes; (void)n_in; (void)out_size; (void)ws_size;

    char* wsb = (char*)d_ws;
    size_t off = 0;
    auto alloc = [&](size_t bytes) -> void* {
        void* p = wsb + off; off = (off + bytes + 255) & ~(size_t)255; return p;
    };
    const size_t BIGE = (size_t)RROWS * DD;
    auto ubuf = [&]() { return (unsigned short*)alloc(BIGE * 2); };
    unsigned short* xm  = ubuf();   // -> retr
    unsigned short* q   = ubuf();   // -> aq
    unsigned short* k   = ubuf();   // -> ak
    unsigned short* v   = ubuf();   // -> dz1
    unsigned short* z1  = ubuf();   // -> av
    unsigned short* h1  = ubuf();   // -> h1r
    unsigned short* d2  = ubuf();   // -> o (attention output)
    unsigned short* dz2 = ubuf();
    unsigned short* kT   = ubuf();
    unsigned short* h1T  = ubuf();
    unsigned short* dz2T = ubuf();
    unsigned short* dz1T = ubuf();
    unsigned short* Wt = (unsigned short*)alloc((size_t)12 * DD * DD * 2);
    float* w   = (float*)alloc((size_t)RROWS * 4);
    float* gW  = (float*)alloc((size_t)2 * DD * DD * 4);
    float* Wn  = (float*)alloc((size_t)2 * DD * DD * 4);
    float* gb  = (float*)alloc(1024 * 4);
    float* bn  = (float*)alloc(1024 * 4);
    auto WT = [&](int i) { return Wt + (size_t)i * DD * DD; };
    // WT slots: 0 WqT 1 WkT 2 WvT 3 W0T 4 W1T 5-8 swaT0-3 9 W1nat 10 Wn0T 11 Wn1T

    // one-time weight transposes/conversions
    TXP tp{};
    tp.s[0] = Wq;             tp.d[0] = WT(0);
    tp.s[1] = Wk;             tp.d[1] = WT(1);
    tp.s[2] = Wv;             tp.d[2] = WT(2);
    tp.s[3] = lmmW;           tp.d[3] = WT(3);
    tp.s[4] = lmmW + DD * DD; tp.d[4] = WT(4);
    tp.s[5] = swaW + 0 * DD * DD; tp.d[5] = WT(5);
    tp.s[6] = swaW + 1 * DD * DD; tp.d[6] = WT(6);
    tp.s[7] = swaW + 2 * DD * DD; tp.d[7] = WT(7);
    tp.s[8] = swaW + 3 * DD * DD; tp.d[8] = WT(8);
    transp_f2b<<<dim3(8, 8, 9), 256, 0, stream>>>(tp);
    convf2b_k<<<(DD * DD + 255) / 256, 256, 0, stream>>>(lmmW + DD * DD, WT(9), DD * DD);
    build_xm_k<<<(int)((BIGE + 255) / 256), 256, 0, stream>>>(x, meta, xm);
    zero_k<<<(2 * DD * DD + 255) / 256, 256, 0, stream>>>(gW, 2 * DD * DD);

    const dim3 gB(256);
    const dim3 gNN(4, 34, 1);   // N=512, M=4352
    const dim3 gTN(4, 4, 4);    // 512x512, split-K=4
    const dim3 gT(8, 68);       // activation transpose
    const dim3 gO(4, 32, 1);    // final M=4096

    // projections + adaptive lr
    mgemm<0><<<gNN, gB, 0, stream>>>(xm, WT(0), bq, nullptr, nullptr, nullptr, q, nullptr, RROWS, DD, DD);
    mgemm<0><<<gNN, gB, 0, stream>>>(xm, WT(1), bk, nullptr, nullptr, nullptr, k, nullptr, RROWS, DD, DD);
    mgemm<0><<<gNN, gB, 0, stream>>>(xm, WT(2), bv, nullptr, nullptr, nullptr, v, nullptr, RROWS, DD, DD);
    lr_k<<<(RROWS * 64 + 255) / 256, gB, 0, stream>>>(xm, Wlr, blr, w);

    // lmm forward on k (fused add-silu; keep z1), then fused pred->d2->dz2
    mgemm<2><<<gNN, gB, 0, stream>>>(k, WT(3), lmmb, k, nullptr, nullptr, h1, z1, RROWS, DD, DD);
    mgemm<3><<<gNN, gB, 0, stream>>>(h1, WT(4), lmmb + DD, h1, v, w, d2, dz2, RROWS, DD, DD);

    // grads: gW1 = h1^T dz2 ; gb1 ; dh1->dz1 fused ; gW0 = k^T dz1 ; gb0
    transp_b2b<<<gT, gB, 0, stream>>>(h1, h1T, RROWS, DD);
    transp_b2b<<<gT, gB, 0, stream>>>(dz2, dz2T, RROWS, DD);
    mgemm<6><<<gTN, gB, 0, stream>>>(h1T, dz2T, nullptr, nullptr, nullptr, nullptr, gW + DD * DD, nullptr, DD, DD, RROWS);
    rowsum_k<<<DD, gB, 0, stream>>>(dz2T, gb + DD, RROWS);
    mgemm<4><<<gNN, gB, 0, stream>>>(dz2, WT(9), nullptr, d2, z1, nullptr, v, nullptr, RROWS, DD, DD); // v := dz1
    transp_b2b<<<gT, gB, 0, stream>>>(k, kT, RROWS, DD);
    transp_b2b<<<gT, gB, 0, stream>>>(v, dz1T, RROWS, DD);
    mgemm<6><<<gTN, gB, 0, stream>>>(kT, dz1T, nullptr, nullptr, nullptr, nullptr, gW, nullptr, DD, DD, RROWS);
    rowsum_k<<<DD, gB, 0, stream>>>(dz1T, gb, RROWS);

    // AdamW-style update + transpose updated weights
    adamw_k<<<(2 * DD * DD + 255) / 256, gB, 0, stream>>>(lmmW, gW, Wn, 2 * DD * DD);
    adamw_k<<<(2 * DD + 255) / 256, gB, 0, stream>>>(lmmb, gb, bn, 2 * DD);
    TXP tp2{};
    tp2.s[0] = Wn;           tp2.d[0] = WT(10);
    tp2.s[1] = Wn + DD * DD; tp2.d[1] = WT(11);
    transp_f2b<<<dim3(8, 8, 2), gB, 0, stream>>>(tp2);

    // retrieval with updated memory
    mgemm<1><<<gNN, gB, 0, stream>>>(q, WT(10), bn, q, nullptr, nullptr, h1, nullptr, RROWS, DD, DD);      // h1 := h1r
    mgemm<1><<<gNN, gB, 0, stream>>>(h1, WT(11), bn + DD, h1, nullptr, nullptr, xm, nullptr, RROWS, DD, DD); // xm := retr

    // SWA projections, attention, out-proj
    mgemm<0><<<gNN, gB, 0, stream>>>(xm, WT(5), swab + 0 * DD, nullptr, nullptr, nullptr, q, nullptr, RROWS, DD, DD);  // aq
    mgemm<0><<<gNN, gB, 0, stream>>>(xm, WT(6), swab + 1 * DD, nullptr, nullptr, nullptr, k, nullptr, RROWS, DD, DD);  // ak
    mgemm<0><<<gNN, gB, 0, stream>>>(xm, WT(7), swab + 2 * DD, nullptr, nullptr, nullptr, z1, nullptr, RROWS, DD, DD); // av
    swa_k<<<BB * HH * SSQ, 128, 0, stream>>>(q, k, z1, d2);   // d2 := o
    mgemm<5><<<gO, gB, 0, stream>>>(d2, WT(8), swab + 3 * DD, nullptr, nullptr, nullptr, out, nullptr, OROWS, DD, DD);
}

// Round 4
// 352.032 us; speedup vs baseline: 8.8812x; 1.4166x over previous
//
#include <hip/hip_runtime.h>
#include <cmath>

// ---------------- problem constants ----------------
constexpr int BB = 4, SSQ = 1024, DD = 512, MM = 64, TTK = MM + SSQ; // 1088
constexpr int HH = 8, HD = DD / HH, WINDOW = 128;
constexpr int RROWS = BB * TTK;     // 4352
constexpr int OROWS = BB * SSQ;     // 4096
constexpr float LR_ = 1e-3f, WD_ = 1e-2f, MAXALR_ = 0.1f, EPS_ = 1e-8f;
constexpr float C2_ = 2.0f / (float)DD;
constexpr int VPAD = 200;           // Vt j-stride (192+8): 25d mod 8 distinct -> conflict-light

typedef short  s16x8 __attribute__((ext_vector_type(8)));
typedef float  f32x4 __attribute__((ext_vector_type(4)));

__device__ __forceinline__ float b2f(unsigned short u) {
    union { unsigned int i; float f; } c; c.i = ((unsigned int)u) << 16; return c.f;
}
__device__ __forceinline__ unsigned short f2b(float f) {
    union { float f; unsigned int i; } c; c.f = f;
    unsigned int r = c.i + 0x7fffu + ((c.i >> 16) & 1u);   // RNE
    return (unsigned short)(r >> 16);
}
__device__ __forceinline__ float sigm(float x) { return 1.f / (1.f + __expf(-x)); }

__device__ __forceinline__ void gld16(const void* g, void* l) {
    __builtin_amdgcn_global_load_lds((const __attribute__((address_space(1))) unsigned int*)g,
                                     (__attribute__((address_space(3))) unsigned int*)l, 16, 0, 0);
}

// ---------------- canonical bf16 MFMA GEMM ----------------
// C[M,N] = sum_k A[m][k]*B[n][k] (+bias[n]) -- A:[M,*] lda-strided k-contig, B:[N,K] k-contig
// EPI: 0 bf16-out | 1 add-silu | 2 add-silu + write z | 3 pred/d2/dz2 | 4 dh1/dz1
//      5 f32-out | 6 f32 atomicAdd (split-K)
template<int EPI>
__global__ __launch_bounds__(256) void mgemm(
    const unsigned short* __restrict__ A, const unsigned short* __restrict__ Bm,
    const float* __restrict__ bias,
    const unsigned short* __restrict__ aux0, const unsigned short* __restrict__ aux1,
    const float* __restrict__ wrow,
    void* __restrict__ out0, unsigned short* __restrict__ out1,
    int M, int N, int K, int lda, int ld0, int ld1)
{
    __shared__ unsigned short As[128 * 32];
    __shared__ unsigned short Bs[128 * 32];
    const int tid = threadIdx.x;
    const int m0 = blockIdx.y * 128, n0 = blockIdx.x * 128;
    const int ktiles = K >> 5;
    const int per = ktiles / gridDim.z;
    const int kt0 = blockIdx.z * per, kt1 = kt0 + per;

    const int sm = tid >> 2, sc = tid & 3;           // staging row / 16B chunk
    const unsigned short* Ag = A + (size_t)(m0 + sm) * lda + sc * 8;
    const unsigned short* Bg = Bm + (size_t)(n0 + sm) * K + sc * 8;

    f32x4 acc[4][4];
#pragma unroll
    for (int i = 0; i < 4; ++i)
#pragma unroll
        for (int j = 0; j < 4; ++j)
#pragma unroll
            for (int r = 0; r < 4; ++r) acc[i][j][r] = 0.f;

    const int lane = tid & 63, wv = tid >> 6;
    const int wr = wv >> 1, wc = wv & 1;             // 2x2 wave grid, 64x64 each
    const int fr = lane & 15, fg = lane >> 4;        // frag row + k-group

    for (int kt = kt0; kt < kt1; ++kt) {
        const int kb = kt << 5;
        gld16(Ag + kb,                   &As[tid * 8]);
        gld16(Ag + (size_t)64 * lda + kb, &As[64 * 32 + tid * 8]);
        gld16(Bg + kb,                   &Bs[tid * 8]);
        gld16(Bg + (size_t)64 * K + kb,   &Bs[64 * 32 + tid * 8]);
        __syncthreads();
        s16x8 a[4], b[4];
#pragma unroll
        for (int i = 0; i < 4; ++i) a[i] = *(const s16x8*)&As[(wr * 64 + i * 16 + fr) * 32 + fg * 8];
#pragma unroll
        for (int j = 0; j < 4; ++j) b[j] = *(const s16x8*)&Bs[(wc * 64 + j * 16 + fr) * 32 + fg * 8];
#pragma unroll
        for (int i = 0; i < 4; ++i)
#pragma unroll
            for (int j = 0; j < 4; ++j)
                acc[i][j] = __builtin_amdgcn_mfma_f32_16x16x32_bf16(a[i], b[j], acc[i][j], 0, 0, 0);
        __syncthreads();
    }

    // epilogue: C/D layout col=lane&15, row=(lane>>4)*4+reg
#pragma unroll
    for (int j = 0; j < 4; ++j) {
        const int col = n0 + wc * 64 + j * 16 + fr;
        const float bj = (EPI == 6 || bias == nullptr) ? 0.f : bias[col];
#pragma unroll
        for (int i = 0; i < 4; ++i) {
            const int rowb = m0 + wr * 64 + i * 16 + fg * 4;
#pragma unroll
            for (int r = 0; r < 4; ++r) {
                const int row = rowb + r;
                const size_t off  = (size_t)row * N + col;
                const size_t off0 = (size_t)row * ld0 + col;
                const size_t off1 = (size_t)row * ld1 + col;
                float val = acc[i][j][r] + bj;
                if (EPI == 0) {
                    ((unsigned short*)out0)[off] = f2b(val);
                } else if (EPI == 1 || EPI == 2) {
                    float base = b2f(aux0[off0]);
                    float h = base + val * sigm(val);
                    ((unsigned short*)out0)[off] = f2b(h);
                    if (EPI == 2) out1[off] = f2b(val);
                } else if (EPI == 3) {
                    float h1 = b2f(aux0[off0]);
                    float pred = h1 + val * sigm(val);
                    float vv = b2f(aux1[off1]);
                    float d2 = C2_ * wrow[row] * (pred - vv);
                    float s = sigm(val);
                    float dz2 = d2 * (s * (1.f + val * (1.f - s)));
                    ((unsigned short*)out0)[off] = f2b(d2);
                    out1[off] = f2b(dz2);
                } else if (EPI == 4) {
                    float dh = val + b2f(aux0[off0]);
                    float z1 = b2f(aux1[off1]);
                    float s = sigm(z1);
                    ((unsigned short*)out0)[off] = f2b(dh * (s * (1.f + z1 * (1.f - s))));
                } else if (EPI == 5) {
                    ((float*)out0)[off] = val;
                } else {
                    atomicAdd((float*)out0 + off, val);
                }
            }
        }
    }
}

// ---------------- transposes ----------------
__global__ __launch_bounds__(256) void transp_b2b(const unsigned short* __restrict__ src,
                                                  unsigned short* __restrict__ dst,
                                                  int R, int C, int sld) {
    __shared__ unsigned short t[64][65];
    int r0 = blockIdx.y * 64, c0 = blockIdx.x * 64;
    int lr = threadIdx.x >> 4, lc = (threadIdx.x & 15) * 4;
#pragma unroll
    for (int rr = 0; rr < 64; rr += 16) {
        ushort4 v = *(const ushort4*)(src + (size_t)(r0 + lr + rr) * sld + c0 + lc);
        t[lr + rr][lc] = v.x; t[lr + rr][lc + 1] = v.y; t[lr + rr][lc + 2] = v.z; t[lr + rr][lc + 3] = v.w;
    }
    __syncthreads();
#pragma unroll
    for (int cc = 0; cc < 64; cc += 16) {
        int c = lr + cc;
        ushort4 o; o.x = t[lc][c]; o.y = t[lc + 1][c]; o.z = t[lc + 2][c]; o.w = t[lc + 3][c];
        *(ushort4*)(dst + (size_t)(c0 + c) * R + r0 + lc) = o;
    }
}

struct TXP { const float* s[9]; unsigned short* d[9]; };
__global__ __launch_bounds__(256) void transp_f2b(TXP p) {   // 512x512 fp32 -> bf16 transposed
    const float* src = p.s[blockIdx.z];
    unsigned short* dst = p.d[blockIdx.z];
    __shared__ unsigned short t[64][65];
    int r0 = blockIdx.y * 64, c0 = blockIdx.x * 64;
    int lr = threadIdx.x >> 4, lc = (threadIdx.x & 15) * 4;
#pragma unroll
    for (int rr = 0; rr < 64; rr += 16) {
        float4 v = *(const float4*)(src + (size_t)(r0 + lr + rr) * 512 + c0 + lc);
        t[lr + rr][lc] = f2b(v.x); t[lr + rr][lc + 1] = f2b(v.y);
        t[lr + rr][lc + 2] = f2b(v.z); t[lr + rr][lc + 3] = f2b(v.w);
    }
    __syncthreads();
#pragma unroll
    for (int cc = 0; cc < 64; cc += 16) {
        int c = lr + cc;
        ushort4 o; o.x = t[lc][c]; o.y = t[lc + 1][c]; o.z = t[lc + 2][c]; o.w = t[lc + 3][c];
        *(ushort4*)(dst + (size_t)(c0 + c) * 512 + r0 + lc) = o;
    }
}

// adamw update fused into f32->bf16 transpose (z selects matrix)
__global__ __launch_bounds__(256) void adamw_transp(const float* __restrict__ W,
                                                    const float* __restrict__ G,
                                                    unsigned short* __restrict__ dstBase) {
    const float* src = W + (size_t)blockIdx.z * DD * DD;
    const float* g   = G + (size_t)blockIdx.z * DD * DD;
    unsigned short* dst = dstBase + (size_t)blockIdx.z * DD * DD;
    __shared__ unsigned short t[64][65];
    int r0 = blockIdx.y * 64, c0 = blockIdx.x * 64;
    int lr = threadIdx.x >> 4, lc = (threadIdx.x & 15) * 4;
#pragma unroll
    for (int rr = 0; rr < 64; rr += 16) {
        size_t base = (size_t)(r0 + lr + rr) * 512 + c0 + lc;
        float4 v = *(const float4*)(src + base);
        float4 gg = *(const float4*)(g + base);
        t[lr + rr][lc]     = f2b(v.x * (1.f - LR_ * WD_) - LR_ * gg.x / (fabsf(gg.x) + EPS_));
        t[lr + rr][lc + 1] = f2b(v.y * (1.f - LR_ * WD_) - LR_ * gg.y / (fabsf(gg.y) + EPS_));
        t[lr + rr][lc + 2] = f2b(v.z * (1.f - LR_ * WD_) - LR_ * gg.z / (fabsf(gg.z) + EPS_));
        t[lr + rr][lc + 3] = f2b(v.w * (1.f - LR_ * WD_) - LR_ * gg.w / (fabsf(gg.w) + EPS_));
    }
    __syncthreads();
#pragma unroll
    for (int cc = 0; cc < 64; cc += 16) {
        int c = lr + cc;
        ushort4 o; o.x = t[lc][c]; o.y = t[lc + 1][c]; o.z = t[lc + 2][c]; o.w = t[lc + 3][c];
        *(ushort4*)(dst + (size_t)(c0 + c) * 512 + r0 + lc) = o;
    }
}

__global__ void convf2b_k(const float* __restrict__ s, unsigned short* __restrict__ d, int n) {
    int i = blockIdx.x * 256 + threadIdx.x;
    if (i < n) d[i] = f2b(s[i]);
}

// ---------------- small kernels ----------------
__global__ void build_xm_k(const float* __restrict__ x, const float* __restrict__ meta,
                           unsigned short* __restrict__ xm) {
    size_t idx = (size_t)blockIdx.x * 256 + threadIdx.x;
    if (idx >= (size_t)RROWS * DD) return;
    int d = (int)(idx % DD);
    int t = (int)((idx / DD) % TTK);
    int b = (int)(idx / ((size_t)DD * TTK));
    float v = (t < MM) ? meta[t * DD + d] : x[((size_t)b * SSQ + (t - MM)) * DD + d];
    xm[idx] = f2b(v);
}

__global__ void adamw_k(const float* __restrict__ p, const float* __restrict__ g,
                        float* __restrict__ out, int n) {
    int i = blockIdx.x * 256 + threadIdx.x;
    if (i >= n) return;
    float gg = g[i];
    out[i] = p[i] * (1.f - LR_ * WD_) - LR_ * gg / (fabsf(gg) + EPS_);
}

__global__ void lr_k(const unsigned short* __restrict__ xm, const float* __restrict__ Wlr,
                     const float* __restrict__ blr, float* __restrict__ w) {
    int gid = blockIdx.x * 256 + threadIdx.x;
    int row = gid >> 6, lane = gid & 63;
    if (row >= RROWS) return;
    const unsigned short* xr = xm + (size_t)row * DD;
    float s = 0.f;
    for (int d = lane; d < DD; d += 64) s += b2f(xr[d]) * Wlr[d];
    for (int off = 32; off; off >>= 1) s += __shfl_down(s, off);
    if (lane == 0) w[row] = MAXALR_ / (1.f + __expf(-(s + blr[0])));
}

__global__ __launch_bounds__(256) void rowsum_k(const unsigned short* __restrict__ src,
                                                float* __restrict__ dst, int C) {
    int row = blockIdx.x;
    const unsigned short* p = src + (size_t)row * C;
    float s = 0.f;
    for (int c = threadIdx.x; c < C; c += 256) s += b2f(p[c]);
    for (int off = 32; off; off >>= 1) s += __shfl_down(s, off);
    __shared__ float sm[4];
    if ((threadIdx.x & 63) == 0) sm[threadIdx.x >> 6] = s;
    __syncthreads();
    if (threadIdx.x == 0) dst[row] = sm[0] + sm[1] + sm[2] + sm[3];
}

__global__ void zero_k(float* p, int n) {
    int i = blockIdx.x * 256 + threadIdx.x;
    if (i < n) p[i] = 0.f;
}

__global__ void cbias_k(const float* bq, const float* bk, const float* bv,
                        const float* sb, float* cb1, float* cb2) {
    int i = blockIdx.x * 256 + threadIdx.x;
    if (i >= 1536) return;
    float v = (i < 512) ? bq[i] : (i < 1024) ? bk[i - 512] : bv[i - 1024];
    cb1[i] = v;
    cb2[i] = sb[i];                          // swab rows 0..2 contiguous
}

// ---------------- MFMA sliding-window attention ----------------
// block = (qt, h, b), 256 thr / 4 waves; wave w owns q rows [16w,16w+16)
// keys j in [i0-128, i0+64) = 192, mask kk>qb && kk<=qb+128 && kk>=kmin
__global__ __launch_bounds__(256) void swa_mfma(const unsigned short* __restrict__ AQ,
                                                unsigned short* __restrict__ O) {
    __shared__ unsigned short Qs[64 * 64];     // XOR-swizzled (chunk ^= row&7)
    __shared__ unsigned short KP[192 * 64];    // K tile, then P tile (64x192)
    __shared__ unsigned short Vt[64 * VPAD];   // V transposed [d][j]

    const int tid = threadIdx.x;
    const int qt = blockIdx.x, h = blockIdx.y, b = blockIdx.z;
    const int i0 = MM + qt * 64;
    const int jbase = i0 - 128;
    const int r_ = tid >> 3, c_ = tid & 7;

#pragma unroll
    for (int rd = 0; rd < 2; ++rd) {           // Q: 64 rows
        int r = rd * 32 + r_;
        const unsigned short* src = AQ + ((size_t)(b * TTK + i0 + r)) * 1536 + h * HD
                                    + ((c_ ^ (r & 7)) * 8);
        gld16(src, &Qs[rd * 2048 + tid * 8]);
    }
#pragma unroll
    for (int rd = 0; rd < 6; ++rd) {           // K: 192 rows (clamp j<0, masked later)
        int r = rd * 32 + r_;
        int j = jbase + r; if (j < 0) j = 0;
        const unsigned short* src = AQ + ((size_t)(b * TTK + j)) * 1536 + 512 + h * HD
                                    + ((c_ ^ (r & 7)) * 8);
        gld16(src, &KP[rd * 2048 + tid * 8]);
    }
#pragma unroll
    for (int rd = 0; rd < 6; ++rd) {           // V: reg-staged transpose
        int r = rd * 32 + r_;
        int j = jbase + r; if (j < 0) j = 0;
        const s16x8 vv = *(const s16x8*)(AQ + ((size_t)(b * TTK + j)) * 1536 + 1024 + h * HD + c_ * 8);
#pragma unroll
        for (int i = 0; i < 8; ++i)
            Vt[(c_ * 8 + i) * VPAD + r] = (unsigned short)vv[i];
    }
    __syncthreads();

    const int lane = tid & 63, w = tid >> 6;
    const int g = lane >> 4, fl = lane & 15;
    const int qA = w * 16 + fl;                // A-frag row
    const int swzA = qA & 7;

    f32x4 sc[12];
#pragma unroll
    for (int t = 0; t < 12; ++t) { sc[t][0] = 0.f; sc[t][1] = 0.f; sc[t][2] = 0.f; sc[t][3] = 0.f; }

#pragma unroll
    for (int ks = 0; ks < 2; ++ks) {           // QK^T, K=64 in 2 steps
        s16x8 af = *(const s16x8*)&Qs[qA * 64 + (((4 * ks + g) ^ swzA) * 8)];
#pragma unroll
        for (int t = 0; t < 12; ++t) {
            int jn = t * 16 + fl;
            s16x8 bf = *(const s16x8*)&KP[jn * 64 + (((4 * ks + g) ^ (jn & 7)) * 8)];
            sc[t] = __builtin_amdgcn_mfma_f32_16x16x32_bf16(af, bf, sc[t], 0, 0, 0);
        }
    }

    const int kmin = (i0 < 128) ? (128 - i0) : 0;
    float mx[4] = {-1e30f, -1e30f, -1e30f, -1e30f};
#pragma unroll
    for (int t = 0; t < 12; ++t) {
        int kk = t * 16 + fl;
#pragma unroll
        for (int r = 0; r < 4; ++r) {
            int qb = w * 16 + g * 4 + r;
            bool m = (kk > qb) && (kk <= qb + 128) && (kk >= kmin);
            float v = m ? sc[t][r] * 0.125f : -1e30f;
            sc[t][r] = v;
            mx[r] = fmaxf(mx[r], v);
        }
    }
#pragma unroll
    for (int r = 0; r < 4; ++r) {              // row max across 16-lane group
        mx[r] = fmaxf(mx[r], __shfl_xor(mx[r], 1));
        mx[r] = fmaxf(mx[r], __shfl_xor(mx[r], 2));
        mx[r] = fmaxf(mx[r], __shfl_xor(mx[r], 4));
        mx[r] = fmaxf(mx[r], __shfl_xor(mx[r], 8));
    }
    float ls[4] = {0.f, 0.f, 0.f, 0.f};
#pragma unroll
    for (int t = 0; t < 12; ++t) {
#pragma unroll
        for (int r = 0; r < 4; ++r) {
            float p = __expf(sc[t][r] - mx[r]);   // masked -> exp(-inf)=0
            sc[t][r] = p;
            ls[r] += p;
        }
    }
#pragma unroll
    for (int r = 0; r < 4; ++r) {
        ls[r] += __shfl_xor(ls[r], 1);
        ls[r] += __shfl_xor(ls[r], 2);
        ls[r] += __shfl_xor(ls[r], 4);
        ls[r] += __shfl_xor(ls[r], 8);
    }

    __syncthreads();                           // all waves done reading K tile

    // write P (unnormalized bf16) over K LDS, swizzled for A-frag reads
#pragma unroll
    for (int t = 0; t < 12; ++t) {
        int kk = t * 16 + fl;
#pragma unroll
        for (int r = 0; r < 4; ++r) {
            int qb = w * 16 + g * 4 + r;
            int ch = (kk >> 3) ^ (qb & 7);
            KP[qb * 192 + ch * 8 + (kk & 7)] = f2b(sc[t][r]);
        }
    }
    __syncthreads();

    f32x4 oacc[4];
#pragma unroll
    for (int dt = 0; dt < 4; ++dt) { oacc[dt][0] = 0.f; oacc[dt][1] = 0.f; oacc[dt][2] = 0.f; oacc[dt][3] = 0.f; }
#pragma unroll
    for (int js = 0; js < 6; ++js) {           // PV, K=192 in 6 steps
        s16x8 pa = *(const s16x8*)&KP[qA * 192 + (((js * 4 + g) ^ swzA) * 8)];
#pragma unroll
        for (int dt = 0; dt < 4; ++dt) {
            s16x8 bv = *(const s16x8*)&Vt[(dt * 16 + fl) * VPAD + js * 32 + g * 8];
            oacc[dt] = __builtin_amdgcn_mfma_f32_16x16x32_bf16(pa, bv, oacc[dt], 0, 0, 0);
        }
    }

    float inv[4];
#pragma unroll
    for (int r = 0; r < 4; ++r) inv[r] = 1.f / ls[r];
#pragma unroll
    for (int dt = 0; dt < 4; ++dt) {
#pragma unroll
        for (int r = 0; r < 4; ++r) {
            int qb = w * 16 + g * 4 + r;
            int srow = qt * 64 + qb;
            int d = dt * 16 + fl;
            O[((size_t)b * SSQ + srow) * DD + h * HD + d] = f2b(oacc[dt][r] * inv[r]);
        }
    }
}

// ---------------- launch ----------------
extern "C" void kernel_launch(void* const* d_in, const int* in_sizes, int n_in,
                              void* d_out, int out_size, void* d_ws, size_t ws_size,
                              hipStream_t stream) {
    const float* x    = (const float*)d_in[0];
    const float* meta = (const float*)d_in[1];
    const float* lmmW = (const float*)d_in[2];
    const float* lmmb = (const float*)d_in[3];
    const float* Wq   = (const float*)d_in[4];
    const float* bq   = (const float*)d_in[5];
    const float* Wk   = (const float*)d_in[6];
    const float* bk   = (const float*)d_in[7];
    const float* Wv   = (const float*)d_in[8];
    const float* bv   = (const float*)d_in[9];
    const float* Wlr  = (const float*)d_in[10];
    const float* blr  = (const float*)d_in[11];
    const float* swaW = (const float*)d_in[12];
    const float* swab = (const float*)d_in[13];
    float* out = (float*)d_out;
    (void)in_sizes; (void)n_in; (void)out_size; (void)ws_size;

    char* wsb = (char*)d_ws;
    size_t off = 0;
    auto alloc = [&](size_t bytes) -> void* {
        void* p = wsb + off; off = (off + bytes + 255) & ~(size_t)255; return p;
    };
    const size_t BIGE = (size_t)RROWS * DD;
    unsigned short* qkv  = (unsigned short*)alloc((size_t)RROWS * 1536 * 2);  // q|k|v, later aq|ak|av
    unsigned short* xm   = (unsigned short*)alloc(BIGE * 2);
    unsigned short* h1   = (unsigned short*)alloc(BIGE * 2);
    unsigned short* z1   = (unsigned short*)alloc(BIGE * 2);
    unsigned short* d2   = (unsigned short*)alloc(BIGE * 2);
    unsigned short* dz2  = (unsigned short*)alloc(BIGE * 2);
    unsigned short* dz1  = (unsigned short*)alloc(BIGE * 2);
    unsigned short* h1r  = (unsigned short*)alloc(BIGE * 2);
    unsigned short* retr = (unsigned short*)alloc(BIGE * 2);
    unsigned short* o    = (unsigned short*)alloc((size_t)OROWS * DD * 2);
    unsigned short* kT   = (unsigned short*)alloc(BIGE * 2);
    unsigned short* h1T  = (unsigned short*)alloc(BIGE * 2);
    unsigned short* dz2T = (unsigned short*)alloc(BIGE * 2);
    unsigned short* dz1T = (unsigned short*)alloc(BIGE * 2);
    unsigned short* Wt   = (unsigned short*)alloc((size_t)12 * DD * DD * 2);
    float* w    = (float*)alloc((size_t)RROWS * 4);
    float* gW   = (float*)alloc((size_t)2 * DD * DD * 4);
    float* gb   = (float*)alloc(1024 * 4);
    float* bn   = (float*)alloc(1024 * 4);
    float* cbQ  = (float*)alloc(1536 * 4);
    float* cbS  = (float*)alloc(1536 * 4);
    auto WT = [&](int i) { return Wt + (size_t)i * DD * DD; };
    // slots: 0-2 Wq/Wk/Wv^T | 3 W0^T | 4 W1^T | 5-8 swa0-3^T | 9 W1 native | 10-11 updated W^T

    TXP tp{};
    tp.s[0] = Wq;             tp.d[0] = WT(0);
    tp.s[1] = Wk;             tp.d[1] = WT(1);
    tp.s[2] = Wv;             tp.d[2] = WT(2);
    tp.s[3] = lmmW;           tp.d[3] = WT(3);
    tp.s[4] = lmmW + DD * DD; tp.d[4] = WT(4);
    tp.s[5] = swaW + 0 * DD * DD; tp.d[5] = WT(5);
    tp.s[6] = swaW + 1 * DD * DD; tp.d[6] = WT(6);
    tp.s[7] = swaW + 2 * DD * DD; tp.d[7] = WT(7);
    tp.s[8] = swaW + 3 * DD * DD; tp.d[8] = WT(8);
    transp_f2b<<<dim3(8, 8, 9), 256, 0, stream>>>(tp);
    convf2b_k<<<(DD * DD + 255) / 256, 256, 0, stream>>>(lmmW + DD * DD, WT(9), DD * DD);
    build_xm_k<<<(int)((BIGE + 255) / 256), 256, 0, stream>>>(x, meta, xm);
    zero_k<<<(2 * DD * DD + 255) / 256, 256, 0, stream>>>(gW, 2 * DD * DD);
    cbias_k<<<6, 256, 0, stream>>>(bq, bk, bv, swab, cbQ, cbS);

    const dim3 gB(256);
    const dim3 gF(12, 34, 1);    // fused N=1536
    const dim3 gNN(4, 34, 1);    // N=512
    const dim3 gTN(4, 4, 17);    // 512x512 K=4352, split-K=17
    const dim3 gT(8, 68);        // activation transpose
    const dim3 gO(4, 32, 1);     // final M=4096

    // fused q|k|v projection + adaptive lr
    mgemm<0><<<gF, gB, 0, stream>>>(xm, WT(0), cbQ, nullptr, nullptr, nullptr, qkv, nullptr,
                                    RROWS, 1536, DD, DD, 0, 0);
    lr_k<<<(RROWS * 64 + 255) / 256, gB, 0, stream>>>(xm, Wlr, blr, w);

    // lmm forward on k, fused epilogues
    mgemm<2><<<gNN, gB, 0, stream>>>(qkv + 512, WT(3), lmmb, qkv + 512, nullptr, nullptr, h1, z1,
                                     RROWS, DD, DD, 1536, 1536, 0);
    mgemm<3><<<gNN, gB, 0, stream>>>(h1, WT(4), lmmb + DD, h1, qkv + 1024, w, d2, dz2,
                                     RROWS, DD, DD, DD, DD, 1536);

    // grads
    transp_b2b<<<gT, gB, 0, stream>>>(h1, h1T, RROWS, DD, DD);
    transp_b2b<<<gT, gB, 0, stream>>>(dz2, dz2T, RROWS, DD, DD);
    mgemm<6><<<gTN, gB, 0, stream>>>(h1T, dz2T, nullptr, nullptr, nullptr, nullptr, gW + DD * DD, nullptr,
                                     DD, DD, RROWS, RROWS, 0, 0);
    rowsum_k<<<DD, gB, 0, stream>>>(dz2T, gb + DD, RROWS);
    mgemm<4><<<gNN, gB, 0, stream>>>(dz2, WT(9), nullptr, d2, z1, nullptr, dz1, nullptr,
                                     RROWS, DD, DD, DD, DD, DD);
    transp_b2b<<<gT, gB, 0, stream>>>(qkv + 512, kT, RROWS, DD, 1536);
    transp_b2b<<<gT, gB, 0, stream>>>(dz1, dz1T, RROWS, DD, DD);
    mgemm<6><<<gTN, gB, 0, stream>>>(kT, dz1T, nullptr, nullptr, nullptr, nullptr, gW, nullptr,
                                     DD, DD, RROWS, RROWS, 0, 0);
    rowsum_k<<<DD, gB, 0, stream>>>(dz1T, gb, RROWS);

    // AdamW: biases plain, weights fused into transpose
    adamw_k<<<(2 * DD + 255) / 256, gB, 0, stream>>>(lmmb, gb, bn, 2 * DD);
    adamw_transp<<<dim3(8, 8, 2), gB, 0, stream>>>(lmmW, gW, WT(10));

    // retrieval with updated memory
    mgemm<1><<<gNN, gB, 0, stream>>>(qkv, WT(10), bn, qkv, nullptr, nullptr, h1r, nullptr,
                                     RROWS, DD, DD, 1536, 1536, 0);
    mgemm<1><<<gNN, gB, 0, stream>>>(h1r, WT(11), bn + DD, h1r, nullptr, nullptr, retr, nullptr,
                                     RROWS, DD, DD, DD, DD, 0);

    // fused SWA projections (reuse qkv buffer), MFMA attention, out-proj
    mgemm<0><<<gF, gB, 0, stream>>>(retr, WT(5), cbS, nullptr, nullptr, nullptr, qkv, nullptr,
                                    RROWS, 1536, DD, DD, 0, 0);
    swa_mfma<<<dim3(16, 8, 4), gB, 0, stream>>>(qkv, o);
    mgemm<5><<<gO, gB, 0, stream>>>(o, WT(8), swab + 3 * DD, nullptr, nullptr, nullptr, out, nullptr,
                                    OROWS, DD, DD, DD, 0, 0);
}

// Round 5
// 329.014 us; speedup vs baseline: 9.5025x; 1.0700x over previous
//
#include <hip/hip_runtime.h>
#include <cmath>

// ---------------- problem constants ----------------
constexpr int BB = 4, SSQ = 1024, DD = 512, MM = 64, TTK = MM + SSQ; // 1088
constexpr int HH = 8, HD = DD / HH, WINDOW = 128;
constexpr int RROWS = BB * TTK;     // 4352
constexpr int OROWS = BB * SSQ;     // 4096
constexpr float LR_ = 1e-3f, WD_ = 1e-2f, MAXALR_ = 0.1f, EPS_ = 1e-8f;
constexpr float C2_ = 2.0f / (float)DD;
constexpr int VPAD = 200;

typedef short  s16x8 __attribute__((ext_vector_type(8)));
typedef float  f32x4 __attribute__((ext_vector_type(4)));

__device__ __forceinline__ float b2f(unsigned short u) {
    union { unsigned int i; float f; } c; c.i = ((unsigned int)u) << 16; return c.f;
}
__device__ __forceinline__ unsigned short f2b(float f) {
    union { float f; unsigned int i; } c; c.f = f;
    unsigned int r = c.i + 0x7fffu + ((c.i >> 16) & 1u);   // RNE
    return (unsigned short)(r >> 16);
}
__device__ __forceinline__ float sigm(float x) { return 1.f / (1.f + __expf(-x)); }

__device__ __forceinline__ void gld16(const void* g, void* l) {
    __builtin_amdgcn_global_load_lds((const __attribute__((address_space(1))) unsigned int*)g,
                                     (__attribute__((address_space(3))) unsigned int*)l, 16, 0, 0);
}

// ---------------- canonical bf16 MFMA GEMM (BK=64, double-buffered prefetch) ----------------
// C[M,N] = sum_k A[m][k]*B[n][k] (+bias[n]) -- A:[M,*] lda-strided k-contig, B:[N,K] k-contig
// EPI: 0 bf16-out | 1 add-silu | 2 add-silu + write z | 3 pred/d2/dz2 | 4 dh1/dz1
//      5 f32-out | 6 f32 atomicAdd (split-K)
// TNN: tile N (128 or 64); tile M fixed 128.  WTR: also write transposed copy
// of the "key" value (EPI3: dz2, else primary bf16) for cols [tc0,tc1) to outT[(col-tc0)*M+row].
template<int EPI, int TNN, bool WTR>
__global__ __launch_bounds__(256) void mgemm(
    const unsigned short* __restrict__ A, const unsigned short* __restrict__ Bm,
    const float* __restrict__ bias,
    const unsigned short* __restrict__ aux0, const unsigned short* __restrict__ aux1,
    const float* __restrict__ wrow,
    void* __restrict__ out0, unsigned short* __restrict__ out1,
    unsigned short* __restrict__ outT, int tc0, int tc1,
    int M, int N, int K, int lda, int ld0, int ld1)
{
    constexpr int NJ = TNN / 32;              // B frags per wave (4 or 2)
    constexpr int NB = TNN / 32;              // B staging passes (4 or 2)
    __shared__ unsigned short As[2][128 * 64];
    __shared__ unsigned short Bs[2][TNN * 64];
    const int tid = threadIdx.x;
    const int m0 = blockIdx.y * 128, n0 = blockIdx.x * TNN;
    const int ktiles = K >> 6;                 // BK=64
    const int per = ktiles / gridDim.z;
    const int kt0 = blockIdx.z * per, kt1 = kt0 + per;

    const int r_ = tid >> 3, c_ = tid & 7;     // 32 rows x 8 chunks per pass

    auto stage = [&](int buf, int kt) {
        const size_t kb = (size_t)kt * 64;
#pragma unroll
        for (int p = 0; p < 4; ++p)
            gld16(A + (size_t)(m0 + p * 32 + r_) * lda + kb + c_ * 8,
                  &As[buf][(p * 32 + r_) * 64 + c_ * 8]);
#pragma unroll
        for (int p = 0; p < NB; ++p)
            gld16(Bm + (size_t)(n0 + p * 32 + r_) * K + kb + c_ * 8,
                  &Bs[buf][(p * 32 + r_) * 64 + c_ * 8]);
    };

    f32x4 acc[4][NJ];
#pragma unroll
    for (int i = 0; i < 4; ++i)
#pragma unroll
        for (int j = 0; j < NJ; ++j)
#pragma unroll
            for (int r = 0; r < 4; ++r) acc[i][j][r] = 0.f;

    const int lane = tid & 63, wv = tid >> 6;
    const int wr = wv >> 1, wc = wv & 1;       // 2x2 wave grid: 64 rows x TNN/2 cols
    const int fr = lane & 15, fg = lane >> 4;

    stage(0, kt0);
    int cur = 0;
    for (int kt = kt0; kt < kt1; ++kt) {
        __syncthreads();                       // drains prefetch of buf[cur]
        if (kt + 1 < kt1) stage(cur ^ 1, kt + 1);  // issue next while computing
#pragma unroll
        for (int ks = 0; ks < 2; ++ks) {
            s16x8 a[4], b[NJ];
#pragma unroll
            for (int i = 0; i < 4; ++i)
                a[i] = *(const s16x8*)&As[cur][(wr * 64 + i * 16 + fr) * 64 + ks * 32 + fg * 8];
#pragma unroll
            for (int j = 0; j < NJ; ++j)
                b[j] = *(const s16x8*)&Bs[cur][(wc * (TNN / 2) + j * 16 + fr) * 64 + ks * 32 + fg * 8];
#pragma unroll
            for (int i = 0; i < 4; ++i)
#pragma unroll
                for (int j = 0; j < NJ; ++j)
                    acc[i][j] = __builtin_amdgcn_mfma_f32_16x16x32_bf16(a[i], b[j], acc[i][j], 0, 0, 0);
        }
        cur ^= 1;
    }

    // epilogue: C/D layout col=lane&15, row=(lane>>4)*4+reg
#pragma unroll
    for (int j = 0; j < NJ; ++j) {
        const int col = n0 + wc * (TNN / 2) + j * 16 + fr;
        const float bj = (EPI == 6 || bias == nullptr) ? 0.f : bias[col];
#pragma unroll
        for (int i = 0; i < 4; ++i) {
            const int rowb = m0 + wr * 64 + i * 16 + fg * 4;
#pragma unroll
            for (int r = 0; r < 4; ++r) {
                const int row = rowb + r;
                const size_t off  = (size_t)row * N + col;
                const size_t off0 = (size_t)row * ld0 + col;
                const size_t off1 = (size_t)row * ld1 + col;
                float val = acc[i][j][r] + bj;
                float tv = val;
                if constexpr (EPI == 0) {
                    ((unsigned short*)out0)[off] = f2b(val);
                } else if constexpr (EPI == 1 || EPI == 2) {
                    float base = b2f(aux0[off0]);
                    float h = base + val * sigm(val);
                    ((unsigned short*)out0)[off] = f2b(h);
                    if constexpr (EPI == 2) out1[off] = f2b(val);
                    tv = h;
                } else if constexpr (EPI == 3) {
                    float h1 = b2f(aux0[off0]);
                    float pred = h1 + val * sigm(val);
                    float vv = b2f(aux1[off1]);
                    float d2 = C2_ * wrow[row] * (pred - vv);
                    float s = sigm(val);
                    float dz2 = d2 * (s * (1.f + val * (1.f - s)));
                    ((unsigned short*)out0)[off] = f2b(d2);
                    out1[off] = f2b(dz2);
                    tv = dz2;
                } else if constexpr (EPI == 4) {
                    float dh = val + b2f(aux0[off0]);
                    float z1 = b2f(aux1[off1]);
                    float s = sigm(z1);
                    float dz1v = dh * (s * (1.f + z1 * (1.f - s)));
                    ((unsigned short*)out0)[off] = f2b(dz1v);
                    tv = dz1v;
                } else if constexpr (EPI == 5) {
                    ((float*)out0)[off] = val;
                } else {
                    atomicAdd((float*)out0 + off, val);
                }
                if constexpr (WTR) {
                    if (col >= tc0 && col < tc1)
                        outT[(size_t)(col - tc0) * M + row] = f2b(tv);
                }
            }
        }
    }
}

// ---------------- weight transposes (f32 -> bf16), slot 9 = straight copy ----------------
struct TXP { const float* s[10]; unsigned short* d[10]; };
__global__ __launch_bounds__(256) void transp_f2b(TXP p) {
    int z = blockIdx.z;
    const float* src = p.s[z];
    unsigned short* dst = p.d[z];
    int r0 = blockIdx.y * 64, c0 = blockIdx.x * 64;
    int lr = threadIdx.x >> 4, lc = (threadIdx.x & 15) * 4;
    if (z == 9) {                              // straight convert copy
#pragma unroll
        for (int rr = 0; rr < 64; rr += 16) {
            size_t base = (size_t)(r0 + lr + rr) * 512 + c0 + lc;
            float4 v = *(const float4*)(src + base);
            ushort4 o; o.x = f2b(v.x); o.y = f2b(v.y); o.z = f2b(v.z); o.w = f2b(v.w);
            *(ushort4*)(dst + base) = o;
        }
        return;
    }
    __shared__ unsigned short t[64][65];
#pragma unroll
    for (int rr = 0; rr < 64; rr += 16) {
        float4 v = *(const float4*)(src + (size_t)(r0 + lr + rr) * 512 + c0 + lc);
        t[lr + rr][lc] = f2b(v.x); t[lr + rr][lc + 1] = f2b(v.y);
        t[lr + rr][lc + 2] = f2b(v.z); t[lr + rr][lc + 3] = f2b(v.w);
    }
    __syncthreads();
#pragma unroll
    for (int cc = 0; cc < 64; cc += 16) {
        int c = lr + cc;
        ushort4 o; o.x = t[lc][c]; o.y = t[lc + 1][c]; o.z = t[lc + 2][c]; o.w = t[lc + 3][c];
        *(ushort4*)(dst + (size_t)(c0 + c) * 512 + r0 + lc) = o;
    }
}

// adamw fused into f32->bf16 transpose; z==2 slice handles the two bias vectors
__global__ __launch_bounds__(256) void adamw_transp(const float* __restrict__ W,
                                                    const float* __restrict__ G,
                                                    unsigned short* __restrict__ dstBase,
                                                    const float* __restrict__ pb,
                                                    const float* __restrict__ gB,
                                                    float* __restrict__ bnOut) {
    if (blockIdx.z == 2) {
        int idx = (blockIdx.y * 8 + blockIdx.x) * 256 + threadIdx.x;
        if (idx < 2 * DD) {
            float gg = gB[idx];
            bnOut[idx] = pb[idx] * (1.f - LR_ * WD_) - LR_ * gg / (fabsf(gg) + EPS_);
        }
        return;
    }
    const float* src = W + (size_t)blockIdx.z * DD * DD;
    const float* g   = G + (size_t)blockIdx.z * DD * DD;
    unsigned short* dst = dstBase + (size_t)blockIdx.z * DD * DD;
    __shared__ unsigned short t[64][65];
    int r0 = blockIdx.y * 64, c0 = blockIdx.x * 64;
    int lr = threadIdx.x >> 4, lc = (threadIdx.x & 15) * 4;
#pragma unroll
    for (int rr = 0; rr < 64; rr += 16) {
        size_t base = (size_t)(r0 + lr + rr) * 512 + c0 + lc;
        float4 v = *(const float4*)(src + base);
        float4 gg = *(const float4*)(g + base);
        t[lr + rr][lc]     = f2b(v.x * (1.f - LR_ * WD_) - LR_ * gg.x / (fabsf(gg.x) + EPS_));
        t[lr + rr][lc + 1] = f2b(v.y * (1.f - LR_ * WD_) - LR_ * gg.y / (fabsf(gg.y) + EPS_));
        t[lr + rr][lc + 2] = f2b(v.z * (1.f - LR_ * WD_) - LR_ * gg.z / (fabsf(gg.z) + EPS_));
        t[lr + rr][lc + 3] = f2b(v.w * (1.f - LR_ * WD_) - LR_ * gg.w / (fabsf(gg.w) + EPS_));
    }
    __syncthreads();
#pragma unroll
    for (int cc = 0; cc < 64; cc += 16) {
        int c = lr + cc;
        ushort4 o; o.x = t[lc][c]; o.y = t[lc + 1][c]; o.z = t[lc + 2][c]; o.w = t[lc + 3][c];
        *(ushort4*)(dst + (size_t)(c0 + c) * 512 + r0 + lc) = o;
    }
}

// ---------------- small kernels ----------------
__global__ void build_xm_k(const float* __restrict__ x, const float* __restrict__ meta,
                           unsigned short* __restrict__ xm) {
    size_t idx = (size_t)blockIdx.x * 256 + threadIdx.x;
    if (idx >= (size_t)RROWS * DD) return;
    int d = (int)(idx % DD);
    int t = (int)((idx / DD) % TTK);
    int b = (int)(idx / ((size_t)DD * TTK));
    float v = (t < MM) ? meta[t * DD + d] : x[((size_t)b * SSQ + (t - MM)) * DD + d];
    xm[idx] = f2b(v);
}

// zero gW (2048 blocks) + build concatenated bias vectors (tail blocks)
__global__ void setup2_k(float* __restrict__ gW,
                         const float* bq, const float* bk, const float* bv,
                         const float* sb, float* cb1, float* cb2) {
    int bid = blockIdx.x;
    if (bid < 2048) { gW[bid * 256 + threadIdx.x] = 0.f; return; }
    int i = (bid - 2048) * 256 + threadIdx.x;
    if (i >= 1536) return;
    float v = (i < 512) ? bq[i] : (i < 1024) ? bk[i - 512] : bv[i - 1024];
    cb1[i] = v;
    cb2[i] = sb[i];
}

__global__ void lr_k(const unsigned short* __restrict__ xm, const float* __restrict__ Wlr,
                     const float* __restrict__ blr, float* __restrict__ w) {
    int gid = blockIdx.x * 256 + threadIdx.x;
    int row = gid >> 6, lane = gid & 63;
    if (row >= RROWS) return;
    const unsigned short* xr = xm + (size_t)row * DD;
    float s = 0.f;
    for (int d = lane; d < DD; d += 64) s += b2f(xr[d]) * Wlr[d];
    for (int off = 32; off; off >>= 1) s += __shfl_down(s, off);
    if (lane == 0) w[row] = MAXALR_ / (1.f + __expf(-(s + blr[0])));
}

__global__ __launch_bounds__(256) void rowsum_k(const unsigned short* __restrict__ src,
                                                float* __restrict__ dst, int C) {
    int row = blockIdx.x;
    const unsigned short* p = src + (size_t)row * C;
    float s = 0.f;
    for (int c = threadIdx.x; c < C; c += 256) s += b2f(p[c]);
    for (int off = 32; off; off >>= 1) s += __shfl_down(s, off);
    __shared__ float sm[4];
    if ((threadIdx.x & 63) == 0) sm[threadIdx.x >> 6] = s;
    __syncthreads();
    if (threadIdx.x == 0) dst[row] = sm[0] + sm[1] + sm[2] + sm[3];
}

// ---------------- MFMA sliding-window attention ----------------
__global__ __launch_bounds__(256) void swa_mfma(const unsigned short* __restrict__ AQ,
                                                unsigned short* __restrict__ O) {
    __shared__ unsigned short Qs[64 * 64];     // XOR-swizzled (chunk ^= row&7)
    __shared__ unsigned short KP[192 * 64];    // K tile, then P tile (64x192)
    __shared__ unsigned short Vt[64 * VPAD];   // V transposed [d][j]

    const int tid = threadIdx.x;
    const int qt = blockIdx.x, h = blockIdx.y, b = blockIdx.z;
    const int i0 = MM + qt * 64;
    const int jbase = i0 - 128;
    const int r_ = tid >> 3, c_ = tid & 7;

#pragma unroll
    for (int rd = 0; rd < 2; ++rd) {
        int r = rd * 32 + r_;
        const unsigned short* src = AQ + ((size_t)(b * TTK + i0 + r)) * 1536 + h * HD
                                    + ((c_ ^ (r & 7)) * 8);
        gld16(src, &Qs[rd * 2048 + tid * 8]);
    }
#pragma unroll
    for (int rd = 0; rd < 6; ++rd) {
        int r = rd * 32 + r_;
        int j = jbase + r; if (j < 0) j = 0;
        const unsigned short* src = AQ + ((size_t)(b * TTK + j)) * 1536 + 512 + h * HD
                                    + ((c_ ^ (r & 7)) * 8);
        gld16(src, &KP[rd * 2048 + tid * 8]);
    }
#pragma unroll
    for (int rd = 0; rd < 6; ++rd) {
        int r = rd * 32 + r_;
        int j = jbase + r; if (j < 0) j = 0;
        const s16x8 vv = *(const s16x8*)(AQ + ((size_t)(b * TTK + j)) * 1536 + 1024 + h * HD + c_ * 8);
#pragma unroll
        for (int i = 0; i < 8; ++i)
            Vt[(c_ * 8 + i) * VPAD + r] = (unsigned short)vv[i];
    }
    __syncthreads();

    const int lane = tid & 63, w = tid >> 6;
    const int g = lane >> 4, fl = lane & 15;
    const int qA = w * 16 + fl;
    const int swzA = qA & 7;

    f32x4 sc[12];
#pragma unroll
    for (int t = 0; t < 12; ++t) { sc[t][0] = 0.f; sc[t][1] = 0.f; sc[t][2] = 0.f; sc[t][3] = 0.f; }

#pragma unroll
    for (int ks = 0; ks < 2; ++ks) {
        s16x8 af = *(const s16x8*)&Qs[qA * 64 + (((4 * ks + g) ^ swzA) * 8)];
#pragma unroll
        for (int t = 0; t < 12; ++t) {
            int jn = t * 16 + fl;
            s16x8 bf = *(const s16x8*)&KP[jn * 64 + (((4 * ks + g) ^ (jn & 7)) * 8)];
            sc[t] = __builtin_amdgcn_mfma_f32_16x16x32_bf16(af, bf, sc[t], 0, 0, 0);
        }
    }

    const int kmin = (i0 < 128) ? (128 - i0) : 0;
    float mx[4] = {-1e30f, -1e30f, -1e30f, -1e30f};
#pragma unroll
    for (int t = 0; t < 12; ++t) {
        int kk = t * 16 + fl;
#pragma unroll
        for (int r = 0; r < 4; ++r) {
            int qb = w * 16 + g * 4 + r;
            bool m = (kk > qb) && (kk <= qb + 128) && (kk >= kmin);
            float v = m ? sc[t][r] * 0.125f : -1e30f;
            sc[t][r] = v;
            mx[r] = fmaxf(mx[r], v);
        }
    }
#pragma unroll
    for (int r = 0; r < 4; ++r) {
        mx[r] = fmaxf(mx[r], __shfl_xor(mx[r], 1));
        mx[r] = fmaxf(mx[r], __shfl_xor(mx[r], 2));
        mx[r] = fmaxf(mx[r], __shfl_xor(mx[r], 4));
        mx[r] = fmaxf(mx[r], __shfl_xor(mx[r], 8));
    }
    float ls[4] = {0.f, 0.f, 0.f, 0.f};
#pragma unroll
    for (int t = 0; t < 12; ++t) {
#pragma unroll
        for (int r = 0; r < 4; ++r) {
            float p = __expf(sc[t][r] - mx[r]);
            sc[t][r] = p;
            ls[r] += p;
        }
    }
#pragma unroll
    for (int r = 0; r < 4; ++r) {
        ls[r] += __shfl_xor(ls[r], 1);
        ls[r] += __shfl_xor(ls[r], 2);
        ls[r] += __shfl_xor(ls[r], 4);
        ls[r] += __shfl_xor(ls[r], 8);
    }

    __syncthreads();

#pragma unroll
    for (int t = 0; t < 12; ++t) {
        int kk = t * 16 + fl;
#pragma unroll
        for (int r = 0; r < 4; ++r) {
            int qb = w * 16 + g * 4 + r;
            int ch = (kk >> 3) ^ (qb & 7);
            KP[qb * 192 + ch * 8 + (kk & 7)] = f2b(sc[t][r]);
        }
    }
    __syncthreads();

    f32x4 oacc[4];
#pragma unroll
    for (int dt = 0; dt < 4; ++dt) { oacc[dt][0] = 0.f; oacc[dt][1] = 0.f; oacc[dt][2] = 0.f; oacc[dt][3] = 0.f; }
#pragma unroll
    for (int js = 0; js < 6; ++js) {
        s16x8 pa = *(const s16x8*)&KP[qA * 192 + (((js * 4 + g) ^ swzA) * 8)];
#pragma unroll
        for (int dt = 0; dt < 4; ++dt) {
            s16x8 bv = *(const s16x8*)&Vt[(dt * 16 + fl) * VPAD + js * 32 + g * 8];
            oacc[dt] = __builtin_amdgcn_mfma_f32_16x16x32_bf16(pa, bv, oacc[dt], 0, 0, 0);
        }
    }

    float inv[4];
#pragma unroll
    for (int r = 0; r < 4; ++r) inv[r] = 1.f / ls[r];
#pragma unroll
    for (int dt = 0; dt < 4; ++dt) {
#pragma unroll
        for (int r = 0; r < 4; ++r) {
            int qb = w * 16 + g * 4 + r;
            int srow = qt * 64 + qb;
            int d = dt * 16 + fl;
            O[((size_t)b * SSQ + srow) * DD + h * HD + d] = f2b(oacc[dt][r] * inv[r]);
        }
    }
}

// ---------------- launch ----------------
extern "C" void kernel_launch(void* const* d_in, const int* in_sizes, int n_in,
                              void* d_out, int out_size, void* d_ws, size_t ws_size,
                              hipStream_t stream) {
    const float* x    = (const float*)d_in[0];
    const float* meta = (const float*)d_in[1];
    const float* lmmW = (const float*)d_in[2];
    const float* lmmb = (const float*)d_in[3];
    const float* Wq   = (const float*)d_in[4];
    const float* bq   = (const float*)d_in[5];
    const float* Wk   = (const float*)d_in[6];
    const float* bk   = (const float*)d_in[7];
    const float* Wv   = (const float*)d_in[8];
    const float* bv   = (const float*)d_in[9];
    const float* Wlr  = (const float*)d_in[10];
    const float* blr  = (const float*)d_in[11];
    const float* swaW = (const float*)d_in[12];
    const float* swab = (const float*)d_in[13];
    float* out = (float*)d_out;
    (void)in_sizes; (void)n_in; (void)out_size; (void)ws_size;

    char* wsb = (char*)d_ws;
    size_t off = 0;
    auto alloc = [&](size_t bytes) -> void* {
        void* p = wsb + off; off = (off + bytes + 255) & ~(size_t)255; return p;
    };
    const size_t BIGE = (size_t)RROWS * DD;
    unsigned short* qkv  = (unsigned short*)alloc((size_t)RROWS * 1536 * 2);  // q|k|v, later aq|ak|av
    unsigned short* xm   = (unsigned short*)alloc(BIGE * 2);
    unsigned short* h1   = (unsigned short*)alloc(BIGE * 2);
    unsigned short* z1   = (unsigned short*)alloc(BIGE * 2);
    unsigned short* d2   = (unsigned short*)alloc(BIGE * 2);
    unsigned short* dz2  = (unsigned short*)alloc(BIGE * 2);
    unsigned short* dz1  = (unsigned short*)alloc(BIGE * 2);
    unsigned short* h1r  = (unsigned short*)alloc(BIGE * 2);
    unsigned short* retr = (unsigned short*)alloc(BIGE * 2);
    unsigned short* o    = (unsigned short*)alloc((size_t)OROWS * DD * 2);
    unsigned short* kT   = (unsigned short*)alloc(BIGE * 2);
    unsigned short* h1T  = (unsigned short*)alloc(BIGE * 2);
    unsigned short* dz2T = (unsigned short*)alloc(BIGE * 2);
    unsigned short* dz1T = (unsigned short*)alloc(BIGE * 2);
    unsigned short* Wt   = (unsigned short*)alloc((size_t)12 * DD * DD * 2);
    float* w    = (float*)alloc((size_t)RROWS * 4);
    float* gW   = (float*)alloc((size_t)2 * DD * DD * 4);
    float* gb   = (float*)alloc(1024 * 4);
    float* bn   = (float*)alloc(1024 * 4);
    float* cbQ  = (float*)alloc(1536 * 4);
    float* cbS  = (float*)alloc(1536 * 4);
    auto WT = [&](int i) { return Wt + (size_t)i * DD * DD; };
    // slots: 0-2 Wq/Wk/Wv^T | 3 W0^T | 4 W1^T | 5-8 swa0-3^T | 9 W1 native | 10-11 updated W^T

    TXP tp{};
    tp.s[0] = Wq;             tp.d[0] = WT(0);
    tp.s[1] = Wk;             tp.d[1] = WT(1);
    tp.s[2] = Wv;             tp.d[2] = WT(2);
    tp.s[3] = lmmW;           tp.d[3] = WT(3);
    tp.s[4] = lmmW + DD * DD; tp.d[4] = WT(4);
    tp.s[5] = swaW + 0 * DD * DD; tp.d[5] = WT(5);
    tp.s[6] = swaW + 1 * DD * DD; tp.d[6] = WT(6);
    tp.s[7] = swaW + 2 * DD * DD; tp.d[7] = WT(7);
    tp.s[8] = swaW + 3 * DD * DD; tp.d[8] = WT(8);
    tp.s[9] = lmmW + DD * DD; tp.d[9] = WT(9);   // straight copy (W1 native)
    transp_f2b<<<dim3(8, 8, 10), 256, 0, stream>>>(tp);
    build_xm_k<<<(int)((BIGE + 255) / 256), 256, 0, stream>>>(x, meta, xm);
    setup2_k<<<2054, 256, 0, stream>>>(gW, bq, bk, bv, swab, cbQ, cbS);

    const dim3 gB(256);
    const dim3 gF(12, 34, 1);    // N=1536, tile 128x128
    const dim3 g64(8, 34, 1);    // N=512, tile 128x64
    const dim3 gTN(4, 4, 17);    // 512x512 K=4352, split-K=17, tile 128x128
    const dim3 gO64(8, 32, 1);   // final M=4096, tile 128x64

    // fused q|k|v projection (also writes kT) + adaptive lr
    mgemm<0, 128, true><<<gF, gB, 0, stream>>>(xm, WT(0), cbQ, nullptr, nullptr, nullptr,
                                               qkv, nullptr, kT, 512, 1024,
                                               RROWS, 1536, DD, DD, 0, 0);
    lr_k<<<(RROWS * 64 + 255) / 256, gB, 0, stream>>>(xm, Wlr, blr, w);

    // lmm forward on k (writes h1 + h1T + z1), then fused pred/d2/dz2 (+dz2T)
    mgemm<2, 64, true><<<g64, gB, 0, stream>>>(qkv + 512, WT(3), lmmb, qkv + 512, nullptr, nullptr,
                                               h1, z1, h1T, 0, 512,
                                               RROWS, DD, DD, 1536, 1536, 0);
    mgemm<3, 64, true><<<g64, gB, 0, stream>>>(h1, WT(4), lmmb + DD, h1, qkv + 1024, w,
                                               d2, dz2, dz2T, 0, 512,
                                               RROWS, DD, DD, DD, DD, 1536);

    // grads
    mgemm<6, 128, false><<<gTN, gB, 0, stream>>>(h1T, dz2T, nullptr, nullptr, nullptr, nullptr,
                                                 gW + DD * DD, nullptr, nullptr, 0, 0,
                                                 DD, DD, RROWS, RROWS, 0, 0);
    rowsum_k<<<DD, gB, 0, stream>>>(dz2T, gb + DD, RROWS);
    mgemm<4, 64, true><<<g64, gB, 0, stream>>>(dz2, WT(9), nullptr, d2, z1, nullptr,
                                               dz1, nullptr, dz1T, 0, 512,
                                               RROWS, DD, DD, DD, DD, DD);
    mgemm<6, 128, false><<<gTN, gB, 0, stream>>>(kT, dz1T, nullptr, nullptr, nullptr, nullptr,
                                                 gW, nullptr, nullptr, 0, 0,
                                                 DD, DD, RROWS, RROWS, 0, 0);
    rowsum_k<<<DD, gB, 0, stream>>>(dz1T, gb, RROWS);

    // AdamW (weights fused into transpose; biases in z==2 slice)
    adamw_transp<<<dim3(8, 8, 3), gB, 0, stream>>>(lmmW, gW, WT(10), lmmb, gb, bn);

    // retrieval with updated memory
    mgemm<1, 64, false><<<g64, gB, 0, stream>>>(qkv, WT(10), bn, qkv, nullptr, nullptr,
                                                h1r, nullptr, nullptr, 0, 0,
                                                RROWS, DD, DD, 1536, 1536, 0);
    mgemm<1, 64, false><<<g64, gB, 0, stream>>>(h1r, WT(11), bn + DD, h1r, nullptr, nullptr,
                                                retr, nullptr, nullptr, 0, 0,
                                                RROWS, DD, DD, DD, DD, 0);

    // fused SWA projections, MFMA attention, out-proj
    mgemm<0, 128, false><<<gF, gB, 0, stream>>>(retr, WT(5), cbS, nullptr, nullptr, nullptr,
                                                qkv, nullptr, nullptr, 0, 0,
                                                RROWS, 1536, DD, DD, 0, 0);
    swa_mfma<<<dim3(16, 8, 4), gB, 0, stream>>>(qkv, o);
    mgemm<5, 64, false><<<gO64, gB, 0, stream>>>(o, WT(8), swab + 3 * DD, nullptr, nullptr, nullptr,
                                                 out, nullptr, nullptr, 0, 0,
                                                 OROWS, DD, DD, DD, 0, 0);
}

// Round 6
// 294.213 us; speedup vs baseline: 10.6265x; 1.1183x over previous
//
#include <hip/hip_runtime.h>
#include <cmath>

// ---------------- problem constants ----------------
constexpr int BB = 4, SSQ = 1024, DD = 512, MM = 64, TTK = MM + SSQ; // 1088
constexpr int HH = 8, HD = DD / HH, WINDOW = 128;
constexpr int RROWS = BB * TTK;     // 4352
constexpr int OROWS = BB * SSQ;     // 4096
constexpr float LR_ = 1e-3f, WD_ = 1e-2f, MAXALR_ = 0.1f, EPS_ = 1e-8f;
constexpr float C2_ = 2.0f / (float)DD;
constexpr int VPAD = 200;

typedef short  s16x8 __attribute__((ext_vector_type(8)));
typedef float  f32x4 __attribute__((ext_vector_type(4)));

__device__ __forceinline__ float b2f(unsigned short u) {
    union { unsigned int i; float f; } c; c.i = ((unsigned int)u) << 16; return c.f;
}
__device__ __forceinline__ unsigned short f2b(float f) {
    union { float f; unsigned int i; } c; c.f = f;
    unsigned int r = c.i + 0x7fffu + ((c.i >> 16) & 1u);   // RNE
    return (unsigned short)(r >> 16);
}
__device__ __forceinline__ float sigm(float x) { return 1.f / (1.f + __expf(-x)); }

__device__ __forceinline__ void gld16(const void* g, void* l) {
    __builtin_amdgcn_global_load_lds((const __attribute__((address_space(1))) unsigned int*)g,
                                     (__attribute__((address_space(3))) unsigned int*)l, 16, 0, 0);
}

// ---------------- canonical bf16 MFMA GEMM ----------------
// 512 threads / 8 waves (2x4), tile 128 x TNN, BK=64, double-buffered prefetch.
// C[M,N] = sum_k A[m][k]*B[n][k] (+bias[n]) -- A:[M,*] lda-strided k-contig, B:[N,K] k-contig
// EPI: 0 bf16-out | 1 add-silu | 2 add-silu + write z | 3 pred/d2/dz2 | 4 dh1/dz1
//      5 f32-out | 6 f32 atomicAdd (split-K)
// WTR: write transposed copy (via LDS bounce) of "key" value for global cols [tc0,tc1)
//      to outT[(col-tc0)*M + row].  GBS: atomic column-sum of key value into gbOut[col].
template<int EPI, int TNN, bool WTR, bool GBS>
__global__ __launch_bounds__(512) void mgemm(
    const unsigned short* __restrict__ A, const unsigned short* __restrict__ Bm,
    const float* __restrict__ bias,
    const unsigned short* __restrict__ aux0, const unsigned short* __restrict__ aux1,
    const float* __restrict__ wrow,
    void* __restrict__ out0, unsigned short* __restrict__ out1,
    unsigned short* __restrict__ outT, int tc0, int tc1, float* __restrict__ gbOut,
    int M, int N, int K, int lda, int ld0, int ld1)
{
    constexpr int WCOLS = TNN / 4;             // cols per wave
    constexpr int NJ = WCOLS / 16;             // B frags per wave
    constexpr int NB = TNN / 64;               // B staging passes
    constexpr int ASZ = 128 * 64;              // one A buffer (shorts)
    constexpr int BSZ = TNN * 64;
    __shared__ __align__(16) unsigned short LB[2 * ASZ + 2 * BSZ];
    __shared__ float gacc[128];

    const int tid = threadIdx.x;
    const int m0 = blockIdx.y * 128, n0 = blockIdx.x * TNN;
    const int ktiles = K >> 6;
    const int per = ktiles / gridDim.z;
    const int kt0 = blockIdx.z * per, kt1 = kt0 + per;

    if (GBS && tid < 128) gacc[tid] = 0.f;

    const int r_ = tid >> 3, c_ = tid & 7;     // 64 rows x 8 chunks per pass

    auto stage = [&](int buf, int kt) {
        const size_t kb = (size_t)kt * 64;
#pragma unroll
        for (int p = 0; p < 2; ++p)
            gld16(A + (size_t)(m0 + p * 64 + r_) * lda + kb + c_ * 8,
                  &LB[buf * ASZ + (p * 64 + r_) * 64 + c_ * 8]);
#pragma unroll
        for (int p = 0; p < NB; ++p)
            gld16(Bm + (size_t)(n0 + p * 64 + r_) * K + kb + c_ * 8,
                  &LB[2 * ASZ + buf * BSZ + (p * 64 + r_) * 64 + c_ * 8]);
    };

    f32x4 acc[4][NJ];
#pragma unroll
    for (int i = 0; i < 4; ++i)
#pragma unroll
        for (int j = 0; j < NJ; ++j)
#pragma unroll
            for (int r = 0; r < 4; ++r) acc[i][j][r] = 0.f;

    const int lane = tid & 63, wv = tid >> 6;
    const int wr = wv & 1, wc = wv >> 1;       // 2 row-halves x 4 col-quarters
    const int fr = lane & 15, fg = lane >> 4;

    stage(0, kt0);
    int cur = 0;
    for (int kt = kt0; kt < kt1; ++kt) {
        __syncthreads();                       // drains prefetch of buf[cur]
        if (kt + 1 < kt1) stage(cur ^ 1, kt + 1);
#pragma unroll
        for (int ks = 0; ks < 2; ++ks) {
            s16x8 a[4], b[NJ];
#pragma unroll
            for (int i = 0; i < 4; ++i)
                a[i] = *(const s16x8*)&LB[cur * ASZ + (wr * 64 + i * 16 + fr) * 64 + ks * 32 + fg * 8];
#pragma unroll
            for (int j = 0; j < NJ; ++j)
                b[j] = *(const s16x8*)&LB[2 * ASZ + cur * BSZ + (wc * WCOLS + j * 16 + fr) * 64 + ks * 32 + fg * 8];
#pragma unroll
            for (int i = 0; i < 4; ++i)
#pragma unroll
                for (int j = 0; j < NJ; ++j)
                    acc[i][j] = __builtin_amdgcn_mfma_f32_16x16x32_bf16(a[i], b[j], acc[i][j], 0, 0, 0);
        }
        cur ^= 1;
    }
    __syncthreads();                           // all waves done with LB before TLDS reuse

    const bool wtr_blk = WTR && (n0 >= tc0) && (n0 < tc1);
    unsigned short* TL = LB;                   // [TNN][136] transposed tile

    float gsum[NJ];
#pragma unroll
    for (int j = 0; j < NJ; ++j) gsum[j] = 0.f;

    // epilogue: C/D layout col=lane&15, row=(lane>>4)*4+reg
#pragma unroll
    for (int j = 0; j < NJ; ++j) {
        const int col = n0 + wc * WCOLS + j * 16 + fr;
        const float bj = (EPI == 6 || bias == nullptr) ? 0.f : bias[col];
#pragma unroll
        for (int i = 0; i < 4; ++i) {
            const int rowb = m0 + wr * 64 + i * 16 + fg * 4;
#pragma unroll
            for (int r = 0; r < 4; ++r) {
                const int row = rowb + r;
                const size_t off  = (size_t)row * N + col;
                const size_t off0 = (size_t)row * ld0 + col;
                const size_t off1 = (size_t)row * ld1 + col;
                float val = acc[i][j][r] + bj;
                float tv = val;
                if constexpr (EPI == 0) {
                    ((unsigned short*)out0)[off] = f2b(val);
                } else if constexpr (EPI == 1 || EPI == 2) {
                    float base = b2f(aux0[off0]);
                    float h = base + val * sigm(val);
                    ((unsigned short*)out0)[off] = f2b(h);
                    if constexpr (EPI == 2) out1[off] = f2b(val);
                    tv = h;
                } else if constexpr (EPI == 3) {
                    float h1 = b2f(aux0[off0]);
                    float pred = h1 + val * sigm(val);
                    float vv = b2f(aux1[off1]);
                    float d2 = C2_ * wrow[row] * (pred - vv);
                    float s = sigm(val);
                    float dz2 = d2 * (s * (1.f + val * (1.f - s)));
                    ((unsigned short*)out0)[off] = f2b(d2);
                    out1[off] = f2b(dz2);
                    tv = dz2;
                } else if constexpr (EPI == 4) {
                    float dh = val + b2f(aux0[off0]);
                    float z1 = b2f(aux1[off1]);
                    float s = sigm(z1);
                    float dz1v = dh * (s * (1.f + z1 * (1.f - s)));
                    ((unsigned short*)out0)[off] = f2b(dz1v);
                    tv = dz1v;
                } else if constexpr (EPI == 5) {
                    ((float*)out0)[off] = val;
                } else {
                    atomicAdd((float*)out0 + off, val);
                }
                if (wtr_blk)
                    TL[(size_t)(col - n0) * 136 + (row - m0)] = f2b(tv);
                if constexpr (GBS) gsum[j] += tv;
            }
        }
    }

    if constexpr (GBS) {
#pragma unroll
        for (int j = 0; j < NJ; ++j) {
            float s = gsum[j];
            s += __shfl_xor(s, 16);
            s += __shfl_xor(s, 32);
            if (lane < 16) atomicAdd(&gacc[wc * WCOLS + j * 16 + fr], s);
        }
    }

    if (wtr_blk || GBS) {
        __syncthreads();
        if (wtr_blk) {
            for (int idx = tid; idx < TNN * 16; idx += 512) {
                int c = idx >> 4, ch = idx & 15;
                s16x8 v = *(const s16x8*)&TL[(size_t)c * 136 + ch * 8];
                *(s16x8*)&outT[(size_t)(n0 - tc0 + c) * M + m0 + ch * 8] = v;
            }
        }
        if (GBS && tid < TNN) atomicAdd(gbOut + n0 + tid, gacc[tid]);
    }
}

// ---------------- mega setup: weight transposes + xm build + zeroing + bias concat ----------------
struct TXP { const float* s[10]; unsigned short* d[10]; };
__global__ __launch_bounds__(256) void mega_setup(TXP p,
    const float* __restrict__ x, const float* __restrict__ meta, unsigned short* __restrict__ xm,
    float* __restrict__ gW, const float* bq, const float* bk, const float* bv,
    const float* sb, float* cb1, float* cb2, float* gb)
{
    const int bid = blockIdx.x, tid = threadIdx.x;
    __shared__ unsigned short t[64][65];
    if (bid < 640) {                           // 10 x (8x8) weight transposes / copies
        int z = bid >> 6;
        const float* src = p.s[z];
        unsigned short* dst = p.d[z];
        int r0 = ((bid >> 3) & 7) * 64, c0 = (bid & 7) * 64;
        int lr = tid >> 4, lc = (tid & 15) * 4;
        if (z == 9) {                          // straight convert copy (W1 native)
#pragma unroll
            for (int rr = 0; rr < 64; rr += 16) {
                size_t base = (size_t)(r0 + lr + rr) * 512 + c0 + lc;
                float4 v = *(const float4*)(src + base);
                ushort4 o; o.x = f2b(v.x); o.y = f2b(v.y); o.z = f2b(v.z); o.w = f2b(v.w);
                *(ushort4*)(dst + base) = o;
            }
            return;
        }
#pragma unroll
        for (int rr = 0; rr < 64; rr += 16) {
            float4 v = *(const float4*)(src + (size_t)(r0 + lr + rr) * 512 + c0 + lc);
            t[lr + rr][lc] = f2b(v.x); t[lr + rr][lc + 1] = f2b(v.y);
            t[lr + rr][lc + 2] = f2b(v.z); t[lr + rr][lc + 3] = f2b(v.w);
        }
        __syncthreads();
#pragma unroll
        for (int cc = 0; cc < 64; cc += 16) {
            int c = lr + cc;
            ushort4 o; o.x = t[lc][c]; o.y = t[lc + 1][c]; o.z = t[lc + 2][c]; o.w = t[lc + 3][c];
            *(ushort4*)(dst + (size_t)(c0 + c) * 512 + r0 + lc) = o;
        }
        return;
    }
    if (bid < 9344) {                          // build xm (bf16)
        size_t idx = (size_t)(bid - 640) * 256 + tid;
        int d = (int)(idx % DD);
        int tt = (int)((idx / DD) % TTK);
        int b = (int)(idx / ((size_t)DD * TTK));
        float v = (tt < MM) ? meta[tt * DD + d] : x[((size_t)b * SSQ + (tt - MM)) * DD + d];
        xm[idx] = f2b(v);
        return;
    }
    if (bid < 11392) {                         // zero gW
        gW[(size_t)(bid - 9344) * 256 + tid] = 0.f;
        return;
    }
    int i = (bid - 11392) * 256 + tid;         // bias concat + zero gb
    if (i < 1536) { 
        float v = (i < 512) ? bq[i] : (i < 1024) ? bk[i - 512] : bv[i - 1024];
        cb1[i] = v; cb2[i] = sb[i];
    } else if (i < 2560) {
        gb[i - 1536] = 0.f;
    }
}

// adamw fused into f32->bf16 transpose; z==2 slice handles the two bias vectors
__global__ __launch_bounds__(256) void adamw_transp(const float* __restrict__ W,
                                                    const float* __restrict__ G,
                                                    unsigned short* __restrict__ dstBase,
                                                    const float* __restrict__ pb,
                                                    const float* __restrict__ gB,
                                                    float* __restrict__ bnOut) {
    if (blockIdx.z == 2) {
        int idx = (blockIdx.y * 8 + blockIdx.x) * 256 + threadIdx.x;
        if (idx < 2 * DD) {
            float gg = gB[idx];
            bnOut[idx] = pb[idx] * (1.f - LR_ * WD_) - LR_ * gg / (fabsf(gg) + EPS_);
        }
        return;
    }
    const float* src = W + (size_t)blockIdx.z * DD * DD;
    const float* g   = G + (size_t)blockIdx.z * DD * DD;
    unsigned short* dst = dstBase + (size_t)blockIdx.z * DD * DD;
    __shared__ unsigned short t[64][65];
    int r0 = blockIdx.y * 64, c0 = blockIdx.x * 64;
    int lr = threadIdx.x >> 4, lc = (threadIdx.x & 15) * 4;
#pragma unroll
    for (int rr = 0; rr < 64; rr += 16) {
        size_t base = (size_t)(r0 + lr + rr) * 512 + c0 + lc;
        float4 v = *(const float4*)(src + base);
        float4 gg = *(const float4*)(g + base);
        t[lr + rr][lc]     = f2b(v.x * (1.f - LR_ * WD_) - LR_ * gg.x / (fabsf(gg.x) + EPS_));
        t[lr + rr][lc + 1] = f2b(v.y * (1.f - LR_ * WD_) - LR_ * gg.y / (fabsf(gg.y) + EPS_));
        t[lr + rr][lc + 2] = f2b(v.z * (1.f - LR_ * WD_) - LR_ * gg.z / (fabsf(gg.z) + EPS_));
        t[lr + rr][lc + 3] = f2b(v.w * (1.f - LR_ * WD_) - LR_ * gg.w / (fabsf(gg.w) + EPS_));
    }
    __syncthreads();
#pragma unroll
    for (int cc = 0; cc < 64; cc += 16) {
        int c = lr + cc;
        ushort4 o; o.x = t[lc][c]; o.y = t[lc + 1][c]; o.z = t[lc + 2][c]; o.w = t[lc + 3][c];
        *(ushort4*)(dst + (size_t)(c0 + c) * 512 + r0 + lc) = o;
    }
}

__global__ void lr_k(const unsigned short* __restrict__ xm, const float* __restrict__ Wlr,
                     const float* __restrict__ blr, float* __restrict__ w) {
    int gid = blockIdx.x * 256 + threadIdx.x;
    int row = gid >> 6, lane = gid & 63;
    if (row >= RROWS) return;
    const unsigned short* xr = xm + (size_t)row * DD;
    float s = 0.f;
    for (int d = lane; d < DD; d += 64) s += b2f(xr[d]) * Wlr[d];
    for (int off = 32; off; off >>= 1) s += __shfl_down(s, off);
    if (lane == 0) w[row] = MAXALR_ / (1.f + __expf(-(s + blr[0])));
}

// ---------------- MFMA sliding-window attention ----------------
__global__ __launch_bounds__(256) void swa_mfma(const unsigned short* __restrict__ AQ,
                                                unsigned short* __restrict__ O) {
    __shared__ unsigned short Qs[64 * 64];     // XOR-swizzled (chunk ^= row&7)
    __shared__ unsigned short KP[192 * 64];    // K tile, then P tile (64x192)
    __shared__ unsigned short Vt[64 * VPAD];   // V transposed [d][j]

    const int tid = threadIdx.x;
    const int qt = blockIdx.x, h = blockIdx.y, b = blockIdx.z;
    const int i0 = MM + qt * 64;
    const int jbase = i0 - 128;
    const int r_ = tid >> 3, c_ = tid & 7;

#pragma unroll
    for (int rd = 0; rd < 2; ++rd) {
        int r = rd * 32 + r_;
        const unsigned short* src = AQ + ((size_t)(b * TTK + i0 + r)) * 1536 + h * HD
                                    + ((c_ ^ (r & 7)) * 8);
        gld16(src, &Qs[rd * 2048 + tid * 8]);
    }
#pragma unroll
    for (int rd = 0; rd < 6; ++rd) {
        int r = rd * 32 + r_;
        int j = jbase + r; if (j < 0) j = 0;
        const unsigned short* src = AQ + ((size_t)(b * TTK + j)) * 1536 + 512 + h * HD
                                    + ((c_ ^ (r & 7)) * 8);
        gld16(src, &KP[rd * 2048 + tid * 8]);
    }
#pragma unroll
    for (int rd = 0; rd < 6; ++rd) {
        int r = rd * 32 + r_;
        int j = jbase + r; if (j < 0) j = 0;
        const s16x8 vv = *(const s16x8*)(AQ + ((size_t)(b * TTK + j)) * 1536 + 1024 + h * HD + c_ * 8);
#pragma unroll
        for (int i = 0; i < 8; ++i)
            Vt[(c_ * 8 + i) * VPAD + r] = (unsigned short)vv[i];
    }
    __syncthreads();

    const int lane = tid & 63, w = tid >> 6;
    const int g = lane >> 4, fl = lane & 15;
    const int qA = w * 16 + fl;
    const int swzA = qA & 7;

    f32x4 sc[12];
#pragma unroll
    for (int t = 0; t < 12; ++t) { sc[t][0] = 0.f; sc[t][1] = 0.f; sc[t][2] = 0.f; sc[t][3] = 0.f; }

#pragma unroll
    for (int ks = 0; ks < 2; ++ks) {
        s16x8 af = *(const s16x8*)&Qs[qA * 64 + (((4 * ks + g) ^ swzA) * 8)];
#pragma unroll
        for (int t = 0; t < 12; ++t) {
            int jn = t * 16 + fl;
            s16x8 bf = *(const s16x8*)&KP[jn * 64 + (((4 * ks + g) ^ (jn & 7)) * 8)];
            sc[t] = __builtin_amdgcn_mfma_f32_16x16x32_bf16(af, bf, sc[t], 0, 0, 0);
        }
    }

    const int kmin = (i0 < 128) ? (128 - i0) : 0;
    float mx[4] = {-1e30f, -1e30f, -1e30f, -1e30f};
#pragma unroll
    for (int t = 0; t < 12; ++t) {
        int kk = t * 16 + fl;
#pragma unroll
        for (int r = 0; r < 4; ++r) {
            int qb = w * 16 + g * 4 + r;
            bool m = (kk > qb) && (kk <= qb + 128) && (kk >= kmin);
            float v = m ? sc[t][r] * 0.125f : -1e30f;
            sc[t][r] = v;
            mx[r] = fmaxf(mx[r], v);
        }
    }
#pragma unroll
    for (int r = 0; r < 4; ++r) {
        mx[r] = fmaxf(mx[r], __shfl_xor(mx[r], 1));
        mx[r] = fmaxf(mx[r], __shfl_xor(mx[r], 2));
        mx[r] = fmaxf(mx[r], __shfl_xor(mx[r], 4));
        mx[r] = fmaxf(mx[r], __shfl_xor(mx[r], 8));
    }
    float ls[4] = {0.f, 0.f, 0.f, 0.f};
#pragma unroll
    for (int t = 0; t < 12; ++t) {
#pragma unroll
        for (int r = 0; r < 4; ++r) {
            float p = __expf(sc[t][r] - mx[r]);
            sc[t][r] = p;
            ls[r] += p;
        }
    }
#pragma unroll
    for (int r = 0; r < 4; ++r) {
        ls[r] += __shfl_xor(ls[r], 1);
        ls[r] += __shfl_xor(ls[r], 2);
        ls[r] += __shfl_xor(ls[r], 4);
        ls[r] += __shfl_xor(ls[r], 8);
    }

    __syncthreads();

#pragma unroll
    for (int t = 0; t < 12; ++t) {
        int kk = t * 16 + fl;
#pragma unroll
        for (int r = 0; r < 4; ++r) {
            int qb = w * 16 + g * 4 + r;
            int ch = (kk >> 3) ^ (qb & 7);
            KP[qb * 192 + ch * 8 + (kk & 7)] = f2b(sc[t][r]);
        }
    }
    __syncthreads();

    f32x4 oacc[4];
#pragma unroll
    for (int dt = 0; dt < 4; ++dt) { oacc[dt][0] = 0.f; oacc[dt][1] = 0.f; oacc[dt][2] = 0.f; oacc[dt][3] = 0.f; }
#pragma unroll
    for (int js = 0; js < 6; ++js) {
        s16x8 pa = *(const s16x8*)&KP[qA * 192 + (((js * 4 + g) ^ swzA) * 8)];
#pragma unroll
        for (int dt = 0; dt < 4; ++dt) {
            s16x8 bv = *(const s16x8*)&Vt[(dt * 16 + fl) * VPAD + js * 32 + g * 8];
            oacc[dt] = __builtin_amdgcn_mfma_f32_16x16x32_bf16(pa, bv, oacc[dt], 0, 0, 0);
        }
    }

    float inv[4];
#pragma unroll
    for (int r = 0; r < 4; ++r) inv[r] = 1.f / ls[r];
#pragma unroll
    for (int dt = 0; dt < 4; ++dt) {
#pragma unroll
        for (int r = 0; r < 4; ++r) {
            int qb = w * 16 + g * 4 + r;
            int srow = qt * 64 + qb;
            int d = dt * 16 + fl;
            O[((size_t)b * SSQ + srow) * DD + h * HD + d] = f2b(oacc[dt][r] * inv[r]);
        }
    }
}

// ---------------- launch ----------------
extern "C" void kernel_launch(void* const* d_in, const int* in_sizes, int n_in,
                              void* d_out, int out_size, void* d_ws, size_t ws_size,
                              hipStream_t stream) {
    const float* x    = (const float*)d_in[0];
    const float* meta = (const float*)d_in[1];
    const float* lmmW = (const float*)d_in[2];
    const float* lmmb = (const float*)d_in[3];
    const float* Wq   = (const float*)d_in[4];
    const float* bq   = (const float*)d_in[5];
    const float* Wk   = (const float*)d_in[6];
    const float* bk   = (const float*)d_in[7];
    const float* Wv   = (const float*)d_in[8];
    const float* bv   = (const float*)d_in[9];
    const float* Wlr  = (const float*)d_in[10];
    const float* blr  = (const float*)d_in[11];
    const float* swaW = (const float*)d_in[12];
    const float* swab = (const float*)d_in[13];
    float* out = (float*)d_out;
    (void)in_sizes; (void)n_in; (void)out_size; (void)ws_size;

    char* wsb = (char*)d_ws;
    size_t off = 0;
    auto alloc = [&](size_t bytes) -> void* {
        void* p = wsb + off; off = (off + bytes + 255) & ~(size_t)255; return p;
    };
    const size_t BIGE = (size_t)RROWS * DD;
    unsigned short* qkv  = (unsigned short*)alloc((size_t)RROWS * 1536 * 2);  // q|k|v, later aq|ak|av
    unsigned short* xm   = (unsigned short*)alloc(BIGE * 2);
    unsigned short* h1   = (unsigned short*)alloc(BIGE * 2);
    unsigned short* z1   = (unsigned short*)alloc(BIGE * 2);
    unsigned short* d2   = (unsigned short*)alloc(BIGE * 2);
    unsigned short* dz2  = (unsigned short*)alloc(BIGE * 2);
    unsigned short* dz1  = (unsigned short*)alloc(BIGE * 2);
    unsigned short* h1r  = (unsigned short*)alloc(BIGE * 2);
    unsigned short* retr = (unsigned short*)alloc(BIGE * 2);
    unsigned short* o    = (unsigned short*)alloc((size_t)OROWS * DD * 2);
    unsigned short* kT   = (unsigned short*)alloc(BIGE * 2);
    unsigned short* h1T  = (unsigned short*)alloc(BIGE * 2);
    unsigned short* dz2T = (unsigned short*)alloc(BIGE * 2);
    unsigned short* dz1T = (unsigned short*)alloc(BIGE * 2);
    unsigned short* Wt   = (unsigned short*)alloc((size_t)12 * DD * DD * 2);
    float* w    = (float*)alloc((size_t)RROWS * 4);
    float* gW   = (float*)alloc((size_t)2 * DD * DD * 4);
    float* gb   = (float*)alloc(1024 * 4);
    float* bn   = (float*)alloc(1024 * 4);
    float* cbQ  = (float*)alloc(1536 * 4);
    float* cbS  = (float*)alloc(1536 * 4);
    auto WT = [&](int i) { return Wt + (size_t)i * DD * DD; };
    // slots: 0-2 Wq/Wk/Wv^T | 3 W0^T | 4 W1^T | 5-8 swa0-3^T | 9 W1 native | 10-11 updated W^T

    TXP tp{};
    tp.s[0] = Wq;             tp.d[0] = WT(0);
    tp.s[1] = Wk;             tp.d[1] = WT(1);
    tp.s[2] = Wv;             tp.d[2] = WT(2);
    tp.s[3] = lmmW;           tp.d[3] = WT(3);
    tp.s[4] = lmmW + DD * DD; tp.d[4] = WT(4);
    tp.s[5] = swaW + 0 * DD * DD; tp.d[5] = WT(5);
    tp.s[6] = swaW + 1 * DD * DD; tp.d[6] = WT(6);
    tp.s[7] = swaW + 2 * DD * DD; tp.d[7] = WT(7);
    tp.s[8] = swaW + 3 * DD * DD; tp.d[8] = WT(8);
    tp.s[9] = lmmW + DD * DD; tp.d[9] = WT(9);   // straight copy (W1 native)
    mega_setup<<<11402, 256, 0, stream>>>(tp, x, meta, xm, gW, bq, bk, bv, swab, cbQ, cbS, gb);

    const dim3 gB(512);
    const dim3 gF(12, 34, 1);    // N=1536, tile 128x128
    const dim3 g64(8, 34, 1);    // N=512, tile 128x64
    const dim3 gTN(4, 4, 17);    // 512x512 K=4352, split-K=17, tile 128x128
    const dim3 gO64(8, 32, 1);   // final M=4096, tile 128x64

    // fused q|k|v projection (writes kT via LDS bounce) + adaptive lr
    mgemm<0, 128, true, false><<<gF, gB, 0, stream>>>(xm, WT(0), cbQ, nullptr, nullptr, nullptr,
                                                      qkv, nullptr, kT, 512, 1024, nullptr,
                                                      RROWS, 1536, DD, DD, 0, 0);
    lr_k<<<(RROWS * 64 + 255) / 256, 256, 0, stream>>>(xm, Wlr, blr, w);

    // lmm forward on k (h1 + h1T + z1), then fused pred/d2/dz2 (+dz2T +gb1)
    mgemm<2, 64, true, false><<<g64, gB, 0, stream>>>(qkv + 512, WT(3), lmmb, qkv + 512, nullptr, nullptr,
                                                      h1, z1, h1T, 0, 512, nullptr,
                                                      RROWS, DD, DD, 1536, 1536, 0);
    mgemm<3, 64, true, true><<<g64, gB, 0, stream>>>(h1, WT(4), lmmb + DD, h1, qkv + 1024, w,
                                                     d2, dz2, dz2T, 0, 512, gb + DD,
                                                     RROWS, DD, DD, DD, DD, 1536);

    // grads
    mgemm<6, 128, false, false><<<gTN, gB, 0, stream>>>(h1T, dz2T, nullptr, nullptr, nullptr, nullptr,
                                                        gW + DD * DD, nullptr, nullptr, 0, 0, nullptr,
                                                        DD, DD, RROWS, RROWS, 0, 0);
    mgemm<4, 64, true, true><<<g64, gB, 0, stream>>>(dz2, WT(9), nullptr, d2, z1, nullptr,
                                                     dz1, nullptr, dz1T, 0, 512, gb,
                                                     RROWS, DD, DD, DD, DD, DD);
    mgemm<6, 128, false, false><<<gTN, gB, 0, stream>>>(kT, dz1T, nullptr, nullptr, nullptr, nullptr,
                                                        gW, nullptr, nullptr, 0, 0, nullptr,
                                                        DD, DD, RROWS, RROWS, 0, 0);

    // AdamW (weights fused into transpose; biases in z==2 slice)
    adamw_transp<<<dim3(8, 8, 3), 256, 0, stream>>>(lmmW, gW, WT(10), lmmb, gb, bn);

    // retrieval with updated memory
    mgemm<1, 64, false, false><<<g64, gB, 0, stream>>>(qkv, WT(10), bn, qkv, nullptr, nullptr,
                                                       h1r, nullptr, nullptr, 0, 0, nullptr,
                                                       RROWS, DD, DD, 1536, 1536, 0);
    mgemm<1, 64, false, false><<<g64, gB, 0, stream>>>(h1r, WT(11), bn + DD, h1r, nullptr, nullptr,
                                                       retr, nullptr, nullptr, 0, 0, nullptr,
                                                       RROWS, DD, DD, DD, DD, 0);

    // fused SWA projections, MFMA attention, out-proj
    mgemm<0, 128, false, false><<<gF, gB, 0, stream>>>(retr, WT(5), cbS, nullptr, nullptr, nullptr,
                                                       qkv, nullptr, nullptr, 0, 0, nullptr,
                                                       RROWS, 1536, DD, DD, 0, 0);
    swa_mfma<<<dim3(16, 8, 4), 256, 0, stream>>>(qkv, o);
    mgemm<5, 64, false, false><<<gO64, gB, 0, stream>>>(o, WT(8), swab + 3 * DD, nullptr, nullptr, nullptr,
                                                        out, nullptr, nullptr, 0, 0, nullptr,
                                                        OROWS, DD, DD, DD, 0, 0);
}

// Round 7
// 236.652 us; speedup vs baseline: 13.2112x; 1.2432x over previous
//
#include <hip/hip_runtime.h>
#include <cmath>

// ---------------- problem constants ----------------
constexpr int BB = 4, SSQ = 1024, DD = 512, MM = 64, TTK = MM + SSQ; // 1088
constexpr int HH = 8, HD = DD / HH, WINDOW = 128;
constexpr int RROWS = BB * TTK;     // 4352
constexpr int OROWS = BB * SSQ;     // 4096
constexpr float LR_ = 1e-3f, WD_ = 1e-2f, MAXALR_ = 0.1f, EPS_ = 1e-8f;
constexpr float C2_ = 2.0f / (float)DD;
constexpr int VPAD = 200;
constexpr int SPLITK = 17;

typedef short  s16x8 __attribute__((ext_vector_type(8)));
typedef float  f32x4 __attribute__((ext_vector_type(4)));

__device__ __forceinline__ float b2f(unsigned short u) {
    union { unsigned int i; float f; } c; c.i = ((unsigned int)u) << 16; return c.f;
}
__device__ __forceinline__ unsigned short f2b(float f) {
    union { float f; unsigned int i; } c; c.f = f;
    unsigned int r = c.i + 0x7fffu + ((c.i >> 16) & 1u);   // RNE
    return (unsigned short)(r >> 16);
}
__device__ __forceinline__ float sigm(float x) { return 1.f / (1.f + __expf(-x)); }

__device__ __forceinline__ void gld16(const void* g, void* l) {
    __builtin_amdgcn_global_load_lds((const __attribute__((address_space(1))) unsigned int*)g,
                                     (__attribute__((address_space(3))) unsigned int*)l, 16, 0, 0);
}

// ---------------- canonical bf16 MFMA GEMM ----------------
// 512 threads / 8 waves (2x4), tile 128 x TNN, BK=64, double-buffered prefetch.
// LDS XOR-swizzle (both-sides): source chunk c^(row&7) -> linear LDS; read chunk^(row&7).
// EPI: 0 bf16-out | 1 add-silu | 2 add-silu + write z | 3 pred/d2/dz2 | 4 dh1/dz1
//      5 f32-out | 6 f32 split-K partial store (out0 + blockIdx.z*ld0)
// WTR: transposed copy (LDS bounce) of key value, cols [tc0,tc1) -> outT[(col-tc0)*M+row]
// GBS: atomic column-sum of key value into gbOut[col]
template<int EPI, int TNN, bool WTR, bool GBS>
__global__ __launch_bounds__(512) void mgemm(
    const unsigned short* __restrict__ A, const unsigned short* __restrict__ Bm,
    const float* __restrict__ bias,
    const unsigned short* __restrict__ aux0, const unsigned short* __restrict__ aux1,
    const float* __restrict__ wrow,
    void* __restrict__ out0, unsigned short* __restrict__ out1,
    unsigned short* __restrict__ outT, int tc0, int tc1, float* __restrict__ gbOut,
    int M, int N, int K, int lda, int ld0, int ld1)
{
    constexpr int WCOLS = TNN / 4;             // cols per wave
    constexpr int NJ = WCOLS / 16;             // B frags per wave
    constexpr int NB = TNN / 64;               // B staging passes
    constexpr int ASZ = 128 * 64;
    constexpr int BSZ = TNN * 64;
    __shared__ __align__(16) unsigned short LB[2 * ASZ + 2 * BSZ];
    __shared__ float gacc[128];

    const int tid = threadIdx.x;
    const int m0 = blockIdx.y * 128, n0 = blockIdx.x * TNN;
    const int ktiles = K >> 6;
    const int per = ktiles / gridDim.z;
    const int kt0 = blockIdx.z * per, kt1 = kt0 + per;

    if (GBS && tid < 128) gacc[tid] = 0.f;

    const int r_ = tid >> 3, c_ = tid & 7;     // 64 rows x 8 chunks per pass

    auto stage = [&](int buf, int kt) {
        const size_t kb = (size_t)kt * 64;
        const int sw = (c_ ^ (r_ & 7)) * 8;    // pre-swizzled source chunk
#pragma unroll
        for (int p = 0; p < 2; ++p) {
            int row = p * 64 + r_;
            gld16(A + (size_t)(m0 + row) * lda + kb + sw,
                  &LB[buf * ASZ + row * 64 + c_ * 8]);
        }
#pragma unroll
        for (int p = 0; p < NB; ++p) {
            int row = p * 64 + r_;
            gld16(Bm + (size_t)(n0 + row) * K + kb + sw,
                  &LB[2 * ASZ + buf * BSZ + row * 64 + c_ * 8]);
        }
    };

    f32x4 acc[4][NJ];
#pragma unroll
    for (int i = 0; i < 4; ++i)
#pragma unroll
        for (int j = 0; j < NJ; ++j)
#pragma unroll
            for (int r = 0; r < 4; ++r) acc[i][j][r] = 0.f;

    const int lane = tid & 63, wv = tid >> 6;
    const int wr = wv & 1, wc = wv >> 1;       // 2 row-halves x 4 col-quarters
    const int fr = lane & 15, fg = lane >> 4;

    stage(0, kt0);
    int cur = 0;
    for (int kt = kt0; kt < kt1; ++kt) {
        __syncthreads();                       // drains prefetch of buf[cur]
        if (kt + 1 < kt1) stage(cur ^ 1, kt + 1);
#pragma unroll
        for (int ks = 0; ks < 2; ++ks) {
            s16x8 a[4], b[NJ];
#pragma unroll
            for (int i = 0; i < 4; ++i) {
                const int arow = wr * 64 + i * 16 + fr;
                a[i] = *(const s16x8*)&LB[cur * ASZ + arow * 64 + (((ks * 4 + fg) ^ (arow & 7)) * 8)];
            }
#pragma unroll
            for (int j = 0; j < NJ; ++j) {
                const int brow = wc * WCOLS + j * 16 + fr;
                b[j] = *(const s16x8*)&LB[2 * ASZ + cur * BSZ + brow * 64 + (((ks * 4 + fg) ^ (brow & 7)) * 8)];
            }
#pragma unroll
            for (int i = 0; i < 4; ++i)
#pragma unroll
                for (int j = 0; j < NJ; ++j)
                    acc[i][j] = __builtin_amdgcn_mfma_f32_16x16x32_bf16(a[i], b[j], acc[i][j], 0, 0, 0);
        }
        cur ^= 1;
    }
    __syncthreads();                           // all waves done with LB before TL reuse

    const bool wtr_blk = WTR && (n0 >= tc0) && (n0 < tc1);
    unsigned short* TL = LB;                   // [TNN][136] transposed tile

    float gsum[NJ];
#pragma unroll
    for (int j = 0; j < NJ; ++j) gsum[j] = 0.f;

    // epilogue: C/D layout col=lane&15, row=(lane>>4)*4+reg
#pragma unroll
    for (int j = 0; j < NJ; ++j) {
        const int col = n0 + wc * WCOLS + j * 16 + fr;
        const float bj = (EPI == 6 || bias == nullptr) ? 0.f : bias[col];
#pragma unroll
        for (int i = 0; i < 4; ++i) {
            const int rowb = m0 + wr * 64 + i * 16 + fg * 4;
#pragma unroll
            for (int r = 0; r < 4; ++r) {
                const int row = rowb + r;
                const size_t off  = (size_t)row * N + col;
                const size_t off0 = (size_t)row * ld0 + col;
                const size_t off1 = (size_t)row * ld1 + col;
                float val = acc[i][j][r] + bj;
                float tv = val;
                if constexpr (EPI == 0) {
                    ((unsigned short*)out0)[off] = f2b(val);
                } else if constexpr (EPI == 1 || EPI == 2) {
                    float base = b2f(aux0[off0]);
                    float h = base + val * sigm(val);
                    ((unsigned short*)out0)[off] = f2b(h);
                    if constexpr (EPI == 2) out1[off] = f2b(val);
                    tv = h;
                } else if constexpr (EPI == 3) {
                    float h1 = b2f(aux0[off0]);
                    float pred = h1 + val * sigm(val);
                    float vv = b2f(aux1[off1]);
                    float d2 = C2_ * wrow[row] * (pred - vv);
                    float s = sigm(val);
                    float dz2 = d2 * (s * (1.f + val * (1.f - s)));
                    ((unsigned short*)out0)[off] = f2b(d2);
                    out1[off] = f2b(dz2);
                    tv = dz2;
                } else if constexpr (EPI == 4) {
                    float dh = val + b2f(aux0[off0]);
                    float z1 = b2f(aux1[off1]);
                    float s = sigm(z1);
                    float dz1v = dh * (s * (1.f + z1 * (1.f - s)));
                    ((unsigned short*)out0)[off] = f2b(dz1v);
                    tv = dz1v;
                } else if constexpr (EPI == 5) {
                    ((float*)out0)[off] = val;
                } else {
                    ((float*)out0)[(size_t)blockIdx.z * ld0 + off] = val;   // split-K partial
                }
                if (wtr_blk)
                    TL[(size_t)(col - n0) * 136 + (row - m0)] = f2b(tv);
                if constexpr (GBS) gsum[j] += tv;
            }
        }
    }

    if constexpr (GBS) {
#pragma unroll
        for (int j = 0; j < NJ; ++j) {
            float s = gsum[j];
            s += __shfl_xor(s, 16);
            s += __shfl_xor(s, 32);
            if (lane < 16) atomicAdd(&gacc[wc * WCOLS + j * 16 + fr], s);
        }
    }

    if (wtr_blk || GBS) {
        __syncthreads();
        if (wtr_blk) {
            for (int idx = tid; idx < TNN * 16; idx += 512) {
                int c = idx >> 4, ch = idx & 15;
                s16x8 v = *(const s16x8*)&TL[(size_t)c * 136 + ch * 8];
                *(s16x8*)&outT[(size_t)(n0 - tc0 + c) * M + m0 + ch * 8] = v;
            }
        }
        if (GBS && tid < TNN) atomicAdd(gbOut + n0 + tid, gacc[tid]);
    }
}

// ---------------- mega setup: weight transposes + xm/lr rows + bias concat ----------------
struct TXP { const float* s[10]; unsigned short* d[10]; };
__global__ __launch_bounds__(256) void mega_setup(TXP p,
    const float* __restrict__ x, const float* __restrict__ meta, unsigned short* __restrict__ xm,
    const float* __restrict__ Wlr, const float* __restrict__ blr, float* __restrict__ w,
    const float* bq, const float* bk, const float* bv,
    const float* sb, float* cb1, float* cb2, float* gb)
{
    const int bid = blockIdx.x, tid = threadIdx.x;
    if (bid < 640) {                           // 10 x (8x8) weight transposes / copies
        __shared__ unsigned short t[64][65];
        int z = bid >> 6;
        const float* src = p.s[z];
        unsigned short* dst = p.d[z];
        int r0 = ((bid >> 3) & 7) * 64, c0 = (bid & 7) * 64;
        int lr = tid >> 4, lc = (tid & 15) * 4;
        if (z == 9) {                          // straight convert copy (W1 native)
#pragma unroll
            for (int rr = 0; rr < 64; rr += 16) {
                size_t base = (size_t)(r0 + lr + rr) * 512 + c0 + lc;
                float4 v = *(const float4*)(src + base);
                ushort4 o; o.x = f2b(v.x); o.y = f2b(v.y); o.z = f2b(v.z); o.w = f2b(v.w);
                *(ushort4*)(dst + base) = o;
            }
            return;
        }
#pragma unroll
        for (int rr = 0; rr < 64; rr += 16) {
            float4 v = *(const float4*)(src + (size_t)(r0 + lr + rr) * 512 + c0 + lc);
            t[lr + rr][lc] = f2b(v.x); t[lr + rr][lc + 1] = f2b(v.y);
            t[lr + rr][lc + 2] = f2b(v.z); t[lr + rr][lc + 3] = f2b(v.w);
        }
        __syncthreads();
#pragma unroll
        for (int cc = 0; cc < 64; cc += 16) {
            int c = lr + cc;
            ushort4 o; o.x = t[lc][c]; o.y = t[lc + 1][c]; o.z = t[lc + 2][c]; o.w = t[lc + 3][c];
            *(ushort4*)(dst + (size_t)(c0 + c) * 512 + r0 + lc) = o;
        }
        return;
    }
    if (bid < 640 + RROWS) {                   // one row: build xm (bf16) + adaptive lr (f32)
        __shared__ float sm[4];
        int row = bid - 640;
        int b = row / TTK, tt = row % TTK;
        const float* src = (tt < MM) ? meta + (size_t)tt * DD
                                     : x + ((size_t)b * SSQ + (tt - MM)) * DD;
        float x0 = src[tid], x1 = src[tid + 256];
        unsigned short* dst = xm + (size_t)row * DD;
        dst[tid] = f2b(x0); dst[tid + 256] = f2b(x1);
        float s = x0 * Wlr[tid] + x1 * Wlr[tid + 256];
        for (int o2 = 32; o2; o2 >>= 1) s += __shfl_down(s, o2);
        if ((tid & 63) == 0) sm[tid >> 6] = s;
        __syncthreads();
        if (tid == 0) w[row] = MAXALR_ / (1.f + __expf(-(sm[0] + sm[1] + sm[2] + sm[3] + blr[0])));
        return;
    }
    int i = (bid - 640 - RROWS) * 256 + tid;   // bias concat + zero gb
    if (i < 1536) {
        float v = (i < 512) ? bq[i] : (i < 1024) ? bk[i - 512] : bv[i - 1024];
        cb1[i] = v; cb2[i] = sb[i];
    } else if (i < 2560) {
        gb[i - 1536] = 0.f;
    }
}

// adamw fused into f32->bf16 transpose, summing SPLITK gradient partials;
// z==2 slice handles the two bias vectors
__global__ __launch_bounds__(256) void adamw_transp(const float* __restrict__ W,
                                                    const float* __restrict__ gWp,
                                                    unsigned short* __restrict__ dstBase,
                                                    const float* __restrict__ pb,
                                                    const float* __restrict__ gB,
                                                    float* __restrict__ bnOut) {
    if (blockIdx.z == 2) {
        int idx = (blockIdx.y * 8 + blockIdx.x) * 256 + threadIdx.x;
        if (idx < 2 * DD) {
            float gg = gB[idx];
            bnOut[idx] = pb[idx] * (1.f - LR_ * WD_) - LR_ * gg / (fabsf(gg) + EPS_);
        }
        return;
    }
    const int m = blockIdx.z;
    const float* src = W + (size_t)m * DD * DD;
    unsigned short* dst = dstBase + (size_t)m * DD * DD;
    __shared__ unsigned short t[64][65];
    int r0 = blockIdx.y * 64, c0 = blockIdx.x * 64;
    int lr = threadIdx.x >> 4, lc = (threadIdx.x & 15) * 4;
#pragma unroll
    for (int rr = 0; rr < 64; rr += 16) {
        size_t base = (size_t)(r0 + lr + rr) * 512 + c0 + lc;
        float4 v = *(const float4*)(src + base);
        float gx = 0.f, gy = 0.f, gz = 0.f, gw = 0.f;
        for (int z = 0; z < SPLITK; ++z) {
            const float4 p4 = *(const float4*)(gWp + ((size_t)z * 2 + m) * DD * DD + base);
            gx += p4.x; gy += p4.y; gz += p4.z; gw += p4.w;
        }
        t[lr + rr][lc]     = f2b(v.x * (1.f - LR_ * WD_) - LR_ * gx / (fabsf(gx) + EPS_));
        t[lr + rr][lc + 1] = f2b(v.y * (1.f - LR_ * WD_) - LR_ * gy / (fabsf(gy) + EPS_));
        t[lr + rr][lc + 2] = f2b(v.z * (1.f - LR_ * WD_) - LR_ * gz / (fabsf(gz) + EPS_));
        t[lr + rr][lc + 3] = f2b(v.w * (1.f - LR_ * WD_) - LR_ * gw / (fabsf(gw) + EPS_));
    }
    __syncthreads();
#pragma unroll
    for (int cc = 0; cc < 64; cc += 16) {
        int c = lr + cc;
        ushort4 o; o.x = t[lc][c]; o.y = t[lc + 1][c]; o.z = t[lc + 2][c]; o.w = t[lc + 3][c];
        *(ushort4*)(dst + (size_t)(c0 + c) * 512 + r0 + lc) = o;
    }
}

// ---------------- MFMA sliding-window attention ----------------
__global__ __launch_bounds__(256) void swa_mfma(const unsigned short* __restrict__ AQ,
                                                unsigned short* __restrict__ O) {
    __shared__ unsigned short Qs[64 * 64];     // XOR-swizzled (chunk ^= row&7)
    __shared__ unsigned short KP[192 * 64];    // K tile, then P tile (64x192)
    __shared__ unsigned short Vt[64 * VPAD];   // V transposed [d][j]

    const int tid = threadIdx.x;
    const int qt = blockIdx.x, h = blockIdx.y, b = blockIdx.z;
    const int i0 = MM + qt * 64;
    const int jbase = i0 - 128;
    const int r_ = tid >> 3, c_ = tid & 7;

#pragma unroll
    for (int rd = 0; rd < 2; ++rd) {
        int r = rd * 32 + r_;
        const unsigned short* src = AQ + ((size_t)(b * TTK + i0 + r)) * 1536 + h * HD
                                    + ((c_ ^ (r & 7)) * 8);
        gld16(src, &Qs[rd * 2048 + tid * 8]);
    }
#pragma unroll
    for (int rd = 0; rd < 6; ++rd) {
        int r = rd * 32 + r_;
        int j = jbase + r; if (j < 0) j = 0;
        const unsigned short* src = AQ + ((size_t)(b * TTK + j)) * 1536 + 512 + h * HD
                                    + ((c_ ^ (r & 7)) * 8);
        gld16(src, &KP[rd * 2048 + tid * 8]);
    }
#pragma unroll
    for (int rd = 0; rd < 6; ++rd) {
        int r = rd * 32 + r_;
        int j = jbase + r; if (j < 0) j = 0;
        const s16x8 vv = *(const s16x8*)(AQ + ((size_t)(b * TTK + j)) * 1536 + 1024 + h * HD + c_ * 8);
#pragma unroll
        for (int i = 0; i < 8; ++i)
            Vt[(c_ * 8 + i) * VPAD + r] = (unsigned short)vv[i];
    }
    __syncthreads();

    const int lane = tid & 63, w = tid >> 6;
    const int g = lane >> 4, fl = lane & 15;
    const int qA = w * 16 + fl;
    const int swzA = qA & 7;

    f32x4 sc[12];
#pragma unroll
    for (int t = 0; t < 12; ++t) { sc[t][0] = 0.f; sc[t][1] = 0.f; sc[t][2] = 0.f; sc[t][3] = 0.f; }

#pragma unroll
    for (int ks = 0; ks < 2; ++ks) {
        s16x8 af = *(const s16x8*)&Qs[qA * 64 + (((4 * ks + g) ^ swzA) * 8)];
#pragma unroll
        for (int t = 0; t < 12; ++t) {
            int jn = t * 16 + fl;
            s16x8 bf = *(const s16x8*)&KP[jn * 64 + (((4 * ks + g) ^ (jn & 7)) * 8)];
            sc[t] = __builtin_amdgcn_mfma_f32_16x16x32_bf16(af, bf, sc[t], 0, 0, 0);
        }
    }

    const int kmin = (i0 < 128) ? (128 - i0) : 0;
    float mx[4] = {-1e30f, -1e30f, -1e30f, -1e30f};
#pragma unroll
    for (int t = 0; t < 12; ++t) {
        int kk = t * 16 + fl;
#pragma unroll
        for (int r = 0; r < 4; ++r) {
            int qb = w * 16 + g * 4 + r;
            bool m = (kk > qb) && (kk <= qb + 128) && (kk >= kmin);
            float v = m ? sc[t][r] * 0.125f : -1e30f;
            sc[t][r] = v;
            mx[r] = fmaxf(mx[r], v);
        }
    }
#pragma unroll
    for (int r = 0; r < 4; ++r) {
        mx[r] = fmaxf(mx[r], __shfl_xor(mx[r], 1));
        mx[r] = fmaxf(mx[r], __shfl_xor(mx[r], 2));
        mx[r] = fmaxf(mx[r], __shfl_xor(mx[r], 4));
        mx[r] = fmaxf(mx[r], __shfl_xor(mx[r], 8));
    }
    float ls[4] = {0.f, 0.f, 0.f, 0.f};
#pragma unroll
    for (int t = 0; t < 12; ++t) {
#pragma unroll
        for (int r = 0; r < 4; ++r) {
            float p = __expf(sc[t][r] - mx[r]);
            sc[t][r] = p;
            ls[r] += p;
        }
    }
#pragma unroll
    for (int r = 0; r < 4; ++r) {
        ls[r] += __shfl_xor(ls[r], 1);
        ls[r] += __shfl_xor(ls[r], 2);
        ls[r] += __shfl_xor(ls[r], 4);
        ls[r] += __shfl_xor(ls[r], 8);
    }

    __syncthreads();

#pragma unroll
    for (int t = 0; t < 12; ++t) {
        int kk = t * 16 + fl;
#pragma unroll
        for (int r = 0; r < 4; ++r) {
            int qb = w * 16 + g * 4 + r;
            int ch = (kk >> 3) ^ (qb & 7);
            KP[qb * 192 + ch * 8 + (kk & 7)] = f2b(sc[t][r]);
        }
    }
    __syncthreads();

    f32x4 oacc[4];
#pragma unroll
    for (int dt = 0; dt < 4; ++dt) { oacc[dt][0] = 0.f; oacc[dt][1] = 0.f; oacc[dt][2] = 0.f; oacc[dt][3] = 0.f; }
#pragma unroll
    for (int js = 0; js < 6; ++js) {
        s16x8 pa = *(const s16x8*)&KP[qA * 192 + (((js * 4 + g) ^ swzA) * 8)];
#pragma unroll
        for (int dt = 0; dt < 4; ++dt) {
            s16x8 bv = *(const s16x8*)&Vt[(dt * 16 + fl) * VPAD + js * 32 + g * 8];
            oacc[dt] = __builtin_amdgcn_mfma_f32_16x16x32_bf16(pa, bv, oacc[dt], 0, 0, 0);
        }
    }

    float inv[4];
#pragma unroll
    for (int r = 0; r < 4; ++r) inv[r] = 1.f / ls[r];
#pragma unroll
    for (int dt = 0; dt < 4; ++dt) {
#pragma unroll
        for (int r = 0; r < 4; ++r) {
            int qb = w * 16 + g * 4 + r;
            int srow = qt * 64 + qb;
            int d = dt * 16 + fl;
            O[((size_t)b * SSQ + srow) * DD + h * HD + d] = f2b(oacc[dt][r] * inv[r]);
        }
    }
}

// ---------------- launch ----------------
extern "C" void kernel_launch(void* const* d_in, const int* in_sizes, int n_in,
                              void* d_out, int out_size, void* d_ws, size_t ws_size,
                              hipStream_t stream) {
    const float* x    = (const float*)d_in[0];
    const float* meta = (const float*)d_in[1];
    const float* lmmW = (const float*)d_in[2];
    const float* lmmb = (const float*)d_in[3];
    const float* Wq   = (const float*)d_in[4];
    const float* bq   = (const float*)d_in[5];
    const float* Wk   = (const float*)d_in[6];
    const float* bk   = (const float*)d_in[7];
    const float* Wv   = (const float*)d_in[8];
    const float* bv   = (const float*)d_in[9];
    const float* Wlr  = (const float*)d_in[10];
    const float* blr  = (const float*)d_in[11];
    const float* swaW = (const float*)d_in[12];
    const float* swab = (const float*)d_in[13];
    float* out = (float*)d_out;
    (void)in_sizes; (void)n_in; (void)out_size; (void)ws_size;

    char* wsb = (char*)d_ws;
    size_t off = 0;
    auto alloc = [&](size_t bytes) -> void* {
        void* p = wsb + off; off = (off + bytes + 255) & ~(size_t)255; return p;
    };
    const size_t BIGE = (size_t)RROWS * DD;
    unsigned short* qkv  = (unsigned short*)alloc((size_t)RROWS * 1536 * 2);  // q|k|v, later aq|ak|av
    unsigned short* xm   = (unsigned short*)alloc(BIGE * 2);
    unsigned short* h1   = (unsigned short*)alloc(BIGE * 2);
    unsigned short* z1   = (unsigned short*)alloc(BIGE * 2);
    unsigned short* d2   = (unsigned short*)alloc(BIGE * 2);
    unsigned short* dz2  = (unsigned short*)alloc(BIGE * 2);
    unsigned short* dz1  = (unsigned short*)alloc(BIGE * 2);
    unsigned short* h1r  = (unsigned short*)alloc(BIGE * 2);
    unsigned short* retr = (unsigned short*)alloc(BIGE * 2);
    unsigned short* o    = (unsigned short*)alloc((size_t)OROWS * DD * 2);
    unsigned short* kT   = (unsigned short*)alloc(BIGE * 2);
    unsigned short* h1T  = (unsigned short*)alloc(BIGE * 2);
    unsigned short* dz2T = (unsigned short*)alloc(BIGE * 2);
    unsigned short* dz1T = (unsigned short*)alloc(BIGE * 2);
    unsigned short* Wt   = (unsigned short*)alloc((size_t)12 * DD * DD * 2);
    float* gWp  = (float*)alloc((size_t)SPLITK * 2 * DD * DD * 4);   // split-K partials
    float* w    = (float*)alloc((size_t)RROWS * 4);
    float* gb   = (float*)alloc(1024 * 4);
    float* bn   = (float*)alloc(1024 * 4);
    float* cbQ  = (float*)alloc(1536 * 4);
    float* cbS  = (float*)alloc(1536 * 4);
    auto WT = [&](int i) { return Wt + (size_t)i * DD * DD; };
    // slots: 0-2 Wq/Wk/Wv^T | 3 W0^T | 4 W1^T | 5-8 swa0-3^T | 9 W1 native | 10-11 updated W^T

    TXP tp{};
    tp.s[0] = Wq;             tp.d[0] = WT(0);
    tp.s[1] = Wk;             tp.d[1] = WT(1);
    tp.s[2] = Wv;             tp.d[2] = WT(2);
    tp.s[3] = lmmW;           tp.d[3] = WT(3);
    tp.s[4] = lmmW + DD * DD; tp.d[4] = WT(4);
    tp.s[5] = swaW + 0 * DD * DD; tp.d[5] = WT(5);
    tp.s[6] = swaW + 1 * DD * DD; tp.d[6] = WT(6);
    tp.s[7] = swaW + 2 * DD * DD; tp.d[7] = WT(7);
    tp.s[8] = swaW + 3 * DD * DD; tp.d[8] = WT(8);
    tp.s[9] = lmmW + DD * DD; tp.d[9] = WT(9);   // straight copy (W1 native)
    mega_setup<<<640 + RROWS + 10, 256, 0, stream>>>(tp, x, meta, xm, Wlr, blr, w,
                                                     bq, bk, bv, swab, cbQ, cbS, gb);

    const dim3 gB(512);
    const dim3 gF(12, 34, 1);    // N=1536, tile 128x128
    const dim3 g64(8, 34, 1);    // N=512, tile 128x64
    const dim3 gTN(4, 4, SPLITK);// 512x512 K=4352, split-K partials
    const dim3 gO64(8, 32, 1);   // final M=4096, tile 128x64

    // fused q|k|v projection (writes kT via LDS bounce)
    mgemm<0, 128, true, false><<<gF, gB, 0, stream>>>(xm, WT(0), cbQ, nullptr, nullptr, nullptr,
                                                      qkv, nullptr, kT, 512, 1024, nullptr,
                                                      RROWS, 1536, DD, DD, 0, 0);

    // lmm forward on k (h1 + h1T + z1), then fused pred/d2/dz2 (+dz2T +gb1)
    mgemm<2, 64, true, false><<<g64, gB, 0, stream>>>(qkv + 512, WT(3), lmmb, qkv + 512, nullptr, nullptr,
                                                      h1, z1, h1T, 0, 512, nullptr,
                                                      RROWS, DD, DD, 1536, 1536, 0);
    mgemm<3, 64, true, true><<<g64, gB, 0, stream>>>(h1, WT(4), lmmb + DD, h1, qkv + 1024, w,
                                                     d2, dz2, dz2T, 0, 512, gb + DD,
                                                     RROWS, DD, DD, DD, DD, 1536);

    // grads (split-K partial stores; reduced in adamw_transp)
    mgemm<6, 128, false, false><<<gTN, gB, 0, stream>>>(h1T, dz2T, nullptr, nullptr, nullptr, nullptr,
                                                        gWp + DD * DD, nullptr, nullptr, 0, 0, nullptr,
                                                        DD, DD, RROWS, RROWS, 2 * DD * DD, 0);
    mgemm<4, 64, true, true><<<g64, gB, 0, stream>>>(dz2, WT(9), nullptr, d2, z1, nullptr,
                                                     dz1, nullptr, dz1T, 0, 512, gb,
                                                     RROWS, DD, DD, DD, DD, DD);
    mgemm<6, 128, false, false><<<gTN, gB, 0, stream>>>(kT, dz1T, nullptr, nullptr, nullptr, nullptr,
                                                        gWp, nullptr, nullptr, 0, 0, nullptr,
                                                        DD, DD, RROWS, RROWS, 2 * DD * DD, 0);

    // AdamW (weights: partial-sum + update + transpose; biases in z==2 slice)
    adamw_transp<<<dim3(8, 8, 3), 256, 0, stream>>>(lmmW, gWp, WT(10), lmmb, gb, bn);

    // retrieval with updated memory
    mgemm<1, 64, false, false><<<g64, gB, 0, stream>>>(qkv, WT(10), bn, qkv, nullptr, nullptr,
                                                       h1r, nullptr, nullptr, 0, 0, nullptr,
                                                       RROWS, DD, DD, 1536, 1536, 0);
    mgemm<1, 64, false, false><<<g64, gB, 0, stream>>>(h1r, WT(11), bn + DD, h1r, nullptr, nullptr,
                                                       retr, nullptr, nullptr, 0, 0, nullptr,
                                                       RROWS, DD, DD, DD, DD, 0);

    // fused SWA projections, MFMA attention, out-proj
    mgemm<0, 128, false, false><<<gF, gB, 0, stream>>>(retr, WT(5), cbS, nullptr, nullptr, nullptr,
                                                       qkv, nullptr, nullptr, 0, 0, nullptr,
                                                       RROWS, 1536, DD, DD, 0, 0);
    swa_mfma<<<dim3(16, 8, 4), 256, 0, stream>>>(qkv, o);
    mgemm<5, 64, false, false><<<gO64, gB, 0, stream>>>(o, WT(8), swab + 3 * DD, nullptr, nullptr, nullptr,
                                                        out, nullptr, nullptr, 0, 0, nullptr,
                                                        OROWS, DD, DD, DD, 0, 0);
}

// Round 8
// 224.910 us; speedup vs baseline: 13.9010x; 1.0522x over previous
//
#include <hip/hip_runtime.h>
#include <cmath>

// ---------------- problem constants ----------------
constexpr int BB = 4, SSQ = 1024, DD = 512, MM = 64, TTK = MM + SSQ; // 1088
constexpr int HH = 8, HD = DD / HH, WINDOW = 128;
constexpr int RROWS = BB * TTK;     // 4352
constexpr int OROWS = BB * SSQ;     // 4096
constexpr float LR_ = 1e-3f, WD_ = 1e-2f, MAXALR_ = 0.1f, EPS_ = 1e-8f;
constexpr float C2_ = 2.0f / (float)DD;
constexpr int VPAD = 200;
constexpr int SPLITK = 17;

typedef short  s16x8 __attribute__((ext_vector_type(8)));
typedef float  f32x4 __attribute__((ext_vector_type(4)));

__device__ __forceinline__ float b2f(unsigned short u) {
    union { unsigned int i; float f; } c; c.i = ((unsigned int)u) << 16; return c.f;
}
__device__ __forceinline__ unsigned short f2b(float f) {
    union { float f; unsigned int i; } c; c.f = f;
    unsigned int r = c.i + 0x7fffu + ((c.i >> 16) & 1u);   // RNE
    return (unsigned short)(r >> 16);
}
__device__ __forceinline__ float sigm(float x) { return 1.f / (1.f + __expf(-x)); }

__device__ __forceinline__ void gld16(const void* g, void* l) {
    __builtin_amdgcn_global_load_lds((const __attribute__((address_space(1))) unsigned int*)g,
                                     (__attribute__((address_space(3))) unsigned int*)l, 16, 0, 0);
}

// ---------------- canonical bf16 MFMA GEMM body ----------------
// 512 threads / 8 waves (2 row-halves x 4 col-quarters), tile TMM x TNN, BK=64,
// double-buffered prefetch, XOR-swizzled LDS (pre-swizzled global source + swizzled read).
// EPI: 0 bf16-out | 1 add-silu | 2 add-silu + write z | 3 pred/d2/dz2 | 4 dh1/dz1
//      5 f32-out | 6 f32 split-K partial store (out0 + bz*ld0)
// WTR: transposed copy (LDS bounce) of key value, cols [tc0,tc1) -> outT[(col-tc0)*M+row]
// GBS: column-sum of key value into gbOut[col]
struct GArgs {
    const unsigned short* A; const unsigned short* Bm;
    const float* bias;
    const unsigned short* aux0; const unsigned short* aux1;
    const float* wrow;
    void* out0; unsigned short* out1;
    unsigned short* outT; int tc0, tc1; float* gbOut;
    int M, N, K, lda, ld0, ld1;
};

template<int EPI, int TMM, int TNN, bool WTR, bool GBS>
__device__ __forceinline__ void mgemm_body(unsigned short* __restrict__ LB, float* __restrict__ gacc,
                                           int bx, int by, int bz, int gz, const GArgs& a, int tid)
{
    constexpr int WCOLS = TNN / 4;             // cols per wave
    constexpr int NJ = WCOLS / 16;             // B frags per wave
    constexpr int NI = TMM / 32;               // A frags per wave (wave covers TMM/2 rows)
    constexpr int APASS = TMM / 64;
    constexpr int BPASS = TNN / 64;
    constexpr int ASZ = TMM * 64;
    constexpr int BSZ = TNN * 64;
    constexpr int TP  = TMM + 8;               // transposed-tile stride
    constexpr int CH  = TMM / 8;               // 8-short chunks per transposed col

    const int m0 = by * TMM, n0 = bx * TNN;
    const int ktiles = a.K >> 6;
    const int per = ktiles / gz;
    const int kt0 = bz * per, kt1 = kt0 + per;

    if (GBS && tid < 128) gacc[tid] = 0.f;

    const int r_ = tid >> 3, c_ = tid & 7;     // 64 rows x 8 chunks per pass

    auto stage = [&](int buf, int kt) {
        const size_t kb = (size_t)kt * 64;
        const int sw = (c_ ^ (r_ & 7)) * 8;    // pre-swizzled source chunk
#pragma unroll
        for (int p = 0; p < APASS; ++p) {
            int row = p * 64 + r_;
            gld16(a.A + (size_t)(m0 + row) * a.lda + kb + sw,
                  &LB[buf * ASZ + row * 64 + c_ * 8]);
        }
#pragma unroll
        for (int p = 0; p < BPASS; ++p) {
            int row = p * 64 + r_;
            gld16(a.Bm + (size_t)(n0 + row) * a.K + kb + sw,
                  &LB[2 * ASZ + buf * BSZ + row * 64 + c_ * 8]);
        }
    };

    f32x4 acc[NI][NJ];
#pragma unroll
    for (int i = 0; i < NI; ++i)
#pragma unroll
        for (int j = 0; j < NJ; ++j)
#pragma unroll
            for (int r = 0; r < 4; ++r) acc[i][j][r] = 0.f;

    const int lane = tid & 63, wv = tid >> 6;
    const int wr = wv & 1, wc = wv >> 1;       // 2 row-halves x 4 col-quarters
    const int fr = lane & 15, fg = lane >> 4;

    stage(0, kt0);
    int cur = 0;
    for (int kt = kt0; kt < kt1; ++kt) {
        __syncthreads();                       // drains prefetch of buf[cur]
        if (kt + 1 < kt1) stage(cur ^ 1, kt + 1);
#pragma unroll
        for (int ks = 0; ks < 2; ++ks) {
            s16x8 av[NI], bv[NJ];
#pragma unroll
            for (int i = 0; i < NI; ++i) {
                const int arow = wr * (TMM / 2) + i * 16 + fr;
                av[i] = *(const s16x8*)&LB[cur * ASZ + arow * 64 + (((ks * 4 + fg) ^ (arow & 7)) * 8)];
            }
#pragma unroll
            for (int j = 0; j < NJ; ++j) {
                const int brow = wc * WCOLS + j * 16 + fr;
                bv[j] = *(const s16x8*)&LB[2 * ASZ + cur * BSZ + brow * 64 + (((ks * 4 + fg) ^ (brow & 7)) * 8)];
            }
#pragma unroll
            for (int i = 0; i < NI; ++i)
#pragma unroll
                for (int j = 0; j < NJ; ++j)
                    acc[i][j] = __builtin_amdgcn_mfma_f32_16x16x32_bf16(av[i], bv[j], acc[i][j], 0, 0, 0);
        }
        cur ^= 1;
    }
    __syncthreads();                           // all waves done with LB before TL reuse

    const bool wtr_blk = WTR && (n0 >= a.tc0) && (n0 < a.tc1);
    unsigned short* TL = LB;                   // [TNN][TP] transposed tile

    float gsum[NJ];
#pragma unroll
    for (int j = 0; j < NJ; ++j) gsum[j] = 0.f;

    // epilogue: C/D layout col=lane&15, row=(lane>>4)*4+reg
#pragma unroll
    for (int j = 0; j < NJ; ++j) {
        const int col = n0 + wc * WCOLS + j * 16 + fr;
        const float bj = (EPI == 6 || a.bias == nullptr) ? 0.f : a.bias[col];
#pragma unroll
        for (int i = 0; i < NI; ++i) {
            const int rowb = m0 + wr * (TMM / 2) + i * 16 + fg * 4;
#pragma unroll
            for (int r = 0; r < 4; ++r) {
                const int row = rowb + r;
                const size_t off  = (size_t)row * a.N + col;
                const size_t off0 = (size_t)row * a.ld0 + col;
                const size_t off1 = (size_t)row * a.ld1 + col;
                float val = acc[i][j][r] + bj;
                float tv = val;
                if constexpr (EPI == 0) {
                    ((unsigned short*)a.out0)[off] = f2b(val);
                } else if constexpr (EPI == 1 || EPI == 2) {
                    float base = b2f(a.aux0[off0]);
                    float h = base + val * sigm(val);
                    ((unsigned short*)a.out0)[off] = f2b(h);
                    if constexpr (EPI == 2) a.out1[off] = f2b(val);
                    tv = h;
                } else if constexpr (EPI == 3) {
                    float h1 = b2f(a.aux0[off0]);
                    float pred = h1 + val * sigm(val);
                    float vv = b2f(a.aux1[off1]);
                    float d2 = C2_ * a.wrow[row] * (pred - vv);
                    float s = sigm(val);
                    float dz2 = d2 * (s * (1.f + val * (1.f - s)));
                    ((unsigned short*)a.out0)[off] = f2b(d2);
                    a.out1[off] = f2b(dz2);
                    tv = dz2;
                } else if constexpr (EPI == 4) {
                    float dh = val + b2f(a.aux0[off0]);
                    float z1 = b2f(a.aux1[off1]);
                    float s = sigm(z1);
                    float dz1v = dh * (s * (1.f + z1 * (1.f - s)));
                    ((unsigned short*)a.out0)[off] = f2b(dz1v);
                    tv = dz1v;
                } else if constexpr (EPI == 5) {
                    ((float*)a.out0)[off] = val;
                } else {
                    ((float*)a.out0)[(size_t)bz * a.ld0 + off] = val;   // split-K partial
                }
                if (wtr_blk)
                    TL[(size_t)(col - n0) * TP + (row - m0)] = f2b(tv);
                if constexpr (GBS) gsum[j] += tv;
            }
        }
    }

    if constexpr (GBS) {
#pragma unroll
        for (int j = 0; j < NJ; ++j) {
            float s = gsum[j];
            s += __shfl_xor(s, 16);
            s += __shfl_xor(s, 32);
            if (lane < 16) atomicAdd(&gacc[wc * WCOLS + j * 16 + fr], s);
        }
    }

    if (wtr_blk || GBS) {
        __syncthreads();
        if (wtr_blk) {
            for (int idx = tid; idx < TNN * CH; idx += 512) {
                int c = idx / CH, ch = idx % CH;
                s16x8 v = *(const s16x8*)&TL[(size_t)c * TP + ch * 8];
                *(s16x8*)&a.outT[(size_t)(n0 - a.tc0 + c) * a.M + m0 + ch * 8] = v;
            }
        }
        if (GBS && tid < TNN) atomicAdd(a.gbOut + n0 + tid, gacc[tid]);
    }
}

template<int EPI, int TMM, int TNN, bool WTR, bool GBS>
__global__ __launch_bounds__(512) void mgemm(GArgs a) {
    __shared__ __align__(16) unsigned short LB[2 * TMM * 64 + 2 * TNN * 64];
    __shared__ float gacc[128];
    mgemm_body<EPI, TMM, TNN, WTR, GBS>(LB, gacc, blockIdx.x, blockIdx.y, blockIdx.z,
                                        gridDim.z, a, threadIdx.x);
}

// merged launch: path A = split-K grad GEMM (64x128, 544 blocks), path B = EPI4 (64x64, 544)
__global__ __launch_bounds__(512) void mgemm_dual(GArgs a1, GArgs a2) {
    __shared__ __align__(16) unsigned short LB[2 * 64 * 64 + 2 * 128 * 64];
    __shared__ float gacc[128];
    int bid = blockIdx.x;
    if (bid < 544) {
        int bz = bid >> 5, rem = bid & 31;
        mgemm_body<6, 64, 128, false, false>(LB, gacc, rem & 3, rem >> 2, bz, SPLITK, a1, threadIdx.x);
    } else {
        bid -= 544;
        mgemm_body<4, 64, 64, true, true>(LB, gacc, bid & 7, bid >> 3, 0, 1, a2, threadIdx.x);
    }
}

// ---------------- mega setup: weight transposes + xm/lr rows + bias concat ----------------
struct TXP { const float* s[10]; unsigned short* d[10]; };
__global__ __launch_bounds__(256) void mega_setup(TXP p,
    const float* __restrict__ x, const float* __restrict__ meta, unsigned short* __restrict__ xm,
    const float* __restrict__ Wlr, const float* __restrict__ blr, float* __restrict__ w,
    const float* bq, const float* bk, const float* bv,
    const float* sb, float* cb1, float* cb2, float* gb)
{
    const int bid = blockIdx.x, tid = threadIdx.x;
    if (bid < 640) {                           // 10 x (8x8) weight transposes / copies
        __shared__ unsigned short t[64][65];
        int z = bid >> 6;
        const float* src = p.s[z];
        unsigned short* dst = p.d[z];
        int r0 = ((bid >> 3) & 7) * 64, c0 = (bid & 7) * 64;
        int lr = tid >> 4, lc = (tid & 15) * 4;
        if (z == 9) {                          // straight convert copy (W1 native)
#pragma unroll
            for (int rr = 0; rr < 64; rr += 16) {
                size_t base = (size_t)(r0 + lr + rr) * 512 + c0 + lc;
                float4 v = *(const float4*)(src + base);
                ushort4 o; o.x = f2b(v.x); o.y = f2b(v.y); o.z = f2b(v.z); o.w = f2b(v.w);
                *(ushort4*)(dst + base) = o;
            }
            return;
        }
#pragma unroll
        for (int rr = 0; rr < 64; rr += 16) {
            float4 v = *(const float4*)(src + (size_t)(r0 + lr + rr) * 512 + c0 + lc);
            t[lr + rr][lc] = f2b(v.x); t[lr + rr][lc + 1] = f2b(v.y);
            t[lr + rr][lc + 2] = f2b(v.z); t[lr + rr][lc + 3] = f2b(v.w);
        }
        __syncthreads();
#pragma unroll
        for (int cc = 0; cc < 64; cc += 16) {
            int c = lr + cc;
            ushort4 o; o.x = t[lc][c]; o.y = t[lc + 1][c]; o.z = t[lc + 2][c]; o.w = t[lc + 3][c];
            *(ushort4*)(dst + (size_t)(c0 + c) * 512 + r0 + lc) = o;
        }
        return;
    }
    if (bid < 640 + RROWS) {                   // one row: build xm (bf16) + adaptive lr (f32)
        __shared__ float sm[4];
        int row = bid - 640;
        int b = row / TTK, tt = row % TTK;
        const float* src = (tt < MM) ? meta + (size_t)tt * DD
                                     : x + ((size_t)b * SSQ + (tt - MM)) * DD;
        float x0 = src[tid], x1 = src[tid + 256];
        unsigned short* dst = xm + (size_t)row * DD;
        dst[tid] = f2b(x0); dst[tid + 256] = f2b(x1);
        float s = x0 * Wlr[tid] + x1 * Wlr[tid + 256];
        for (int o2 = 32; o2; o2 >>= 1) s += __shfl_down(s, o2);
        if ((tid & 63) == 0) sm[tid >> 6] = s;
        __syncthreads();
        if (tid == 0) w[row] = MAXALR_ / (1.f + __expf(-(sm[0] + sm[1] + sm[2] + sm[3] + blr[0])));
        return;
    }
    int i = (bid - 640 - RROWS) * 256 + tid;   // bias concat + zero gb
    if (i < 1536) {
        float v = (i < 512) ? bq[i] : (i < 1024) ? bk[i - 512] : bv[i - 1024];
        cb1[i] = v; cb2[i] = sb[i];
    } else if (i < 2560) {
        gb[i - 1536] = 0.f;
    }
}

// adamw fused into f32->bf16 transpose, summing SPLITK gradient partials;
// z==2 slice handles the two bias vectors
__global__ __launch_bounds__(256) void adamw_transp(const float* __restrict__ W,
                                                    const float* __restrict__ gWp,
                                                    unsigned short* __restrict__ dstBase,
                                                    const float* __restrict__ pb,
                                                    const float* __restrict__ gB,
                                                    float* __restrict__ bnOut) {
    if (blockIdx.z == 2) {
        int idx = (blockIdx.y * 8 + blockIdx.x) * 256 + threadIdx.x;
        if (idx < 2 * DD) {
            float gg = gB[idx];
            bnOut[idx] = pb[idx] * (1.f - LR_ * WD_) - LR_ * gg / (fabsf(gg) + EPS_);
        }
        return;
    }
    const int m = blockIdx.z;
    const float* src = W + (size_t)m * DD * DD;
    unsigned short* dst = dstBase + (size_t)m * DD * DD;
    __shared__ unsigned short t[64][65];
    int r0 = blockIdx.y * 64, c0 = blockIdx.x * 64;
    int lr = threadIdx.x >> 4, lc = (threadIdx.x & 15) * 4;
#pragma unroll
    for (int rr = 0; rr < 64; rr += 16) {
        size_t base = (size_t)(r0 + lr + rr) * 512 + c0 + lc;
        float4 v = *(const float4*)(src + base);
        float gx = 0.f, gy = 0.f, gz = 0.f, gw = 0.f;
        for (int z = 0; z < SPLITK; ++z) {
            const float4 p4 = *(const float4*)(gWp + ((size_t)z * 2 + m) * DD * DD + base);
            gx += p4.x; gy += p4.y; gz += p4.z; gw += p4.w;
        }
        t[lr + rr][lc]     = f2b(v.x * (1.f - LR_ * WD_) - LR_ * gx / (fabsf(gx) + EPS_));
        t[lr + rr][lc + 1] = f2b(v.y * (1.f - LR_ * WD_) - LR_ * gy / (fabsf(gy) + EPS_));
        t[lr + rr][lc + 2] = f2b(v.z * (1.f - LR_ * WD_) - LR_ * gz / (fabsf(gz) + EPS_));
        t[lr + rr][lc + 3] = f2b(v.w * (1.f - LR_ * WD_) - LR_ * gw / (fabsf(gw) + EPS_));
    }
    __syncthreads();
#pragma unroll
    for (int cc = 0; cc < 64; cc += 16) {
        int c = lr + cc;
        ushort4 o; o.x = t[lc][c]; o.y = t[lc + 1][c]; o.z = t[lc + 2][c]; o.w = t[lc + 3][c];
        *(ushort4*)(dst + (size_t)(c0 + c) * 512 + r0 + lc) = o;
    }
}

// ---------------- MFMA sliding-window attention ----------------
__global__ __launch_bounds__(256) void swa_mfma(const unsigned short* __restrict__ AQ,
                                                unsigned short* __restrict__ O) {
    __shared__ unsigned short Qs[64 * 64];     // XOR-swizzled (chunk ^= row&7)
    __shared__ unsigned short KP[192 * 64];    // K tile, then P tile (64x192)
    __shared__ unsigned short Vt[64 * VPAD];   // V transposed [d][j]

    const int tid = threadIdx.x;
    const int qt = blockIdx.x, h = blockIdx.y, b = blockIdx.z;
    const int i0 = MM + qt * 64;
    const int jbase = i0 - 128;
    const int r_ = tid >> 3, c_ = tid & 7;

#pragma unroll
    for (int rd = 0; rd < 2; ++rd) {
        int r = rd * 32 + r_;
        const unsigned short* src = AQ + ((size_t)(b * TTK + i0 + r)) * 1536 + h * HD
                                    + ((c_ ^ (r & 7)) * 8);
        gld16(src, &Qs[rd * 2048 + tid * 8]);
    }
#pragma unroll
    for (int rd = 0; rd < 6; ++rd) {
        int r = rd * 32 + r_;
        int j = jbase + r; if (j < 0) j = 0;
        const unsigned short* src = AQ + ((size_t)(b * TTK + j)) * 1536 + 512 + h * HD
                                    + ((c_ ^ (r & 7)) * 8);
        gld16(src, &KP[rd * 2048 + tid * 8]);
    }
#pragma unroll
    for (int rd = 0; rd < 6; ++rd) {
        int r = rd * 32 + r_;
        int j = jbase + r; if (j < 0) j = 0;
        const s16x8 vv = *(const s16x8*)(AQ + ((size_t)(b * TTK + j)) * 1536 + 1024 + h * HD + c_ * 8);
#pragma unroll
        for (int i = 0; i < 8; ++i)
            Vt[(c_ * 8 + i) * VPAD + r] = (unsigned short)vv[i];
    }
    __syncthreads();

    const int lane = tid & 63, w = tid >> 6;
    const int g = lane >> 4, fl = lane & 15;
    const int qA = w * 16 + fl;
    const int swzA = qA & 7;

    f32x4 sc[12];
#pragma unroll
    for (int t = 0; t < 12; ++t) { sc[t][0] = 0.f; sc[t][1] = 0.f; sc[t][2] = 0.f; sc[t][3] = 0.f; }

#pragma unroll
    for (int ks = 0; ks < 2; ++ks) {
        s16x8 af = *(const s16x8*)&Qs[qA * 64 + (((4 * ks + g) ^ swzA) * 8)];
#pragma unroll
        for (int t = 0; t < 12; ++t) {
            int jn = t * 16 + fl;
            s16x8 bf = *(const s16x8*)&KP[jn * 64 + (((4 * ks + g) ^ (jn & 7)) * 8)];
            sc[t] = __builtin_amdgcn_mfma_f32_16x16x32_bf16(af, bf, sc[t], 0, 0, 0);
        }
    }

    const int kmin = (i0 < 128) ? (128 - i0) : 0;
    float mx[4] = {-1e30f, -1e30f, -1e30f, -1e30f};
#pragma unroll
    for (int t = 0; t < 12; ++t) {
        int kk = t * 16 + fl;
#pragma unroll
        for (int r = 0; r < 4; ++r) {
            int qb = w * 16 + g * 4 + r;
            bool m = (kk > qb) && (kk <= qb + 128) && (kk >= kmin);
            float v = m ? sc[t][r] * 0.125f : -1e30f;
            sc[t][r] = v;
            mx[r] = fmaxf(mx[r], v);
        }
    }
#pragma unroll
    for (int r = 0; r < 4; ++r) {
        mx[r] = fmaxf(mx[r], __shfl_xor(mx[r], 1));
        mx[r] = fmaxf(mx[r], __shfl_xor(mx[r], 2));
        mx[r] = fmaxf(mx[r], __shfl_xor(mx[r], 4));
        mx[r] = fmaxf(mx[r], __shfl_xor(mx[r], 8));
    }
    float ls[4] = {0.f, 0.f, 0.f, 0.f};
#pragma unroll
    for (int t = 0; t < 12; ++t) {
#pragma unroll
        for (int r = 0; r < 4; ++r) {
            float p = __expf(sc[t][r] - mx[r]);
            sc[t][r] = p;
            ls[r] += p;
        }
    }
#pragma unroll
    for (int r = 0; r < 4; ++r) {
        ls[r] += __shfl_xor(ls[r], 1);
        ls[r] += __shfl_xor(ls[r], 2);
        ls[r] += __shfl_xor(ls[r], 4);
        ls[r] += __shfl_xor(ls[r], 8);
    }

    __syncthreads();

#pragma unroll
    for (int t = 0; t < 12; ++t) {
        int kk = t * 16 + fl;
#pragma unroll
        for (int r = 0; r < 4; ++r) {
            int qb = w * 16 + g * 4 + r;
            int ch = (kk >> 3) ^ (qb & 7);
            KP[qb * 192 + ch * 8 + (kk & 7)] = f2b(sc[t][r]);
        }
    }
    __syncthreads();

    f32x4 oacc[4];
#pragma unroll
    for (int dt = 0; dt < 4; ++dt) { oacc[dt][0] = 0.f; oacc[dt][1] = 0.f; oacc[dt][2] = 0.f; oacc[dt][3] = 0.f; }
#pragma unroll
    for (int js = 0; js < 6; ++js) {
        s16x8 pa = *(const s16x8*)&KP[qA * 192 + (((js * 4 + g) ^ swzA) * 8)];
#pragma unroll
        for (int dt = 0; dt < 4; ++dt) {
            s16x8 bv = *(const s16x8*)&Vt[(dt * 16 + fl) * VPAD + js * 32 + g * 8];
            oacc[dt] = __builtin_amdgcn_mfma_f32_16x16x32_bf16(pa, bv, oacc[dt], 0, 0, 0);
        }
    }

    float inv[4];
#pragma unroll
    for (int r = 0; r < 4; ++r) inv[r] = 1.f / ls[r];
#pragma unroll
    for (int dt = 0; dt < 4; ++dt) {
#pragma unroll
        for (int r = 0; r < 4; ++r) {
            int qb = w * 16 + g * 4 + r;
            int srow = qt * 64 + qb;
            int d = dt * 16 + fl;
            O[((size_t)b * SSQ + srow) * DD + h * HD + d] = f2b(oacc[dt][r] * inv[r]);
        }
    }
}

// ---------------- launch ----------------
extern "C" void kernel_launch(void* const* d_in, const int* in_sizes, int n_in,
                              void* d_out, int out_size, void* d_ws, size_t ws_size,
                              hipStream_t stream) {
    const float* x    = (const float*)d_in[0];
    const float* meta = (const float*)d_in[1];
    const float* lmmW = (const float*)d_in[2];
    const float* lmmb = (const float*)d_in[3];
    const float* Wq   = (const float*)d_in[4];
    const float* bq   = (const float*)d_in[5];
    const float* Wk   = (const float*)d_in[6];
    const float* bk   = (const float*)d_in[7];
    const float* Wv   = (const float*)d_in[8];
    const float* bv   = (const float*)d_in[9];
    const float* Wlr  = (const float*)d_in[10];
    const float* blr  = (const float*)d_in[11];
    const float* swaW = (const float*)d_in[12];
    const float* swab = (const float*)d_in[13];
    float* out = (float*)d_out;
    (void)in_sizes; (void)n_in; (void)out_size; (void)ws_size;

    char* wsb = (char*)d_ws;
    size_t off = 0;
    auto alloc = [&](size_t bytes) -> void* {
        void* p = wsb + off; off = (off + bytes + 255) & ~(size_t)255; return p;
    };
    const size_t BIGE = (size_t)RROWS * DD;
    unsigned short* qkv  = (unsigned short*)alloc((size_t)RROWS * 1536 * 2);  // q|k|v, later aq|ak|av
    unsigned short* xm   = (unsigned short*)alloc(BIGE * 2);
    unsigned short* h1   = (unsigned short*)alloc(BIGE * 2);
    unsigned short* z1   = (unsigned short*)alloc(BIGE * 2);
    unsigned short* d2   = (unsigned short*)alloc(BIGE * 2);
    unsigned short* dz2  = (unsigned short*)alloc(BIGE * 2);
    unsigned short* dz1  = (unsigned short*)alloc(BIGE * 2);
    unsigned short* h1r  = (unsigned short*)alloc(BIGE * 2);
    unsigned short* retr = (unsigned short*)alloc(BIGE * 2);
    unsigned short* o    = (unsigned short*)alloc((size_t)OROWS * DD * 2);
    unsigned short* kT   = (unsigned short*)alloc(BIGE * 2);
    unsigned short* h1T  = (unsigned short*)alloc(BIGE * 2);
    unsigned short* dz2T = (unsigned short*)alloc(BIGE * 2);
    unsigned short* dz1T = (unsigned short*)alloc(BIGE * 2);
    unsigned short* Wt   = (unsigned short*)alloc((size_t)12 * DD * DD * 2);
    float* gWp  = (float*)alloc((size_t)SPLITK * 2 * DD * DD * 4);   // split-K partials
    float* w    = (float*)alloc((size_t)RROWS * 4);
    float* gb   = (float*)alloc(1024 * 4);
    float* bn   = (float*)alloc(1024 * 4);
    float* cbQ  = (float*)alloc(1536 * 4);
    float* cbS  = (float*)alloc(1536 * 4);
    auto WT = [&](int i) { return Wt + (size_t)i * DD * DD; };
    // slots: 0-2 Wq/Wk/Wv^T | 3 W0^T | 4 W1^T | 5-8 swa0-3^T | 9 W1 native | 10-11 updated W^T

    TXP tp{};
    tp.s[0] = Wq;             tp.d[0] = WT(0);
    tp.s[1] = Wk;             tp.d[1] = WT(1);
    tp.s[2] = Wv;             tp.d[2] = WT(2);
    tp.s[3] = lmmW;           tp.d[3] = WT(3);
    tp.s[4] = lmmW + DD * DD; tp.d[4] = WT(4);
    tp.s[5] = swaW + 0 * DD * DD; tp.d[5] = WT(5);
    tp.s[6] = swaW + 1 * DD * DD; tp.d[6] = WT(6);
    tp.s[7] = swaW + 2 * DD * DD; tp.d[7] = WT(7);
    tp.s[8] = swaW + 3 * DD * DD; tp.d[8] = WT(8);
    tp.s[9] = lmmW + DD * DD; tp.d[9] = WT(9);   // straight copy (W1 native)
    mega_setup<<<640 + RROWS + 10, 256, 0, stream>>>(tp, x, meta, xm, Wlr, blr, w,
                                                     bq, bk, bv, swab, cbQ, cbS, gb);

    auto ga = [](const unsigned short* A, const unsigned short* Bm, const float* bias,
                 const unsigned short* a0, const unsigned short* a1, const float* wr,
                 void* o0, unsigned short* o1, unsigned short* oT, int t0, int t1, float* gbo,
                 int M, int N, int K, int lda, int l0, int l1) {
        GArgs g{A, Bm, bias, a0, a1, wr, o0, o1, oT, t0, t1, gbo, M, N, K, lda, l0, l1};
        return g;
    };
    const dim3 gB(512);

    // fused q|k|v projection (writes kT via LDS bounce)
    mgemm<0, 64, 128, true, false><<<dim3(12, 68), gB, 0, stream>>>(
        ga(xm, WT(0), cbQ, nullptr, nullptr, nullptr, qkv, nullptr, kT, 512, 1024, nullptr,
           RROWS, 1536, DD, DD, 0, 0));

    // lmm forward on k (h1 + h1T + z1), then fused pred/d2/dz2 (+dz2T +gb1)
    mgemm<2, 64, 64, true, false><<<dim3(8, 68), gB, 0, stream>>>(
        ga(qkv + 512, WT(3), lmmb, qkv + 512, nullptr, nullptr, h1, z1, h1T, 0, 512, nullptr,
           RROWS, DD, DD, 1536, 1536, 0));
    mgemm<3, 64, 64, true, true><<<dim3(8, 68), gB, 0, stream>>>(
        ga(h1, WT(4), lmmb + DD, h1, qkv + 1024, w, d2, dz2, dz2T, 0, 512, gb + DD,
           RROWS, DD, DD, DD, DD, 1536));

    // gW1 grad (split-K partials) MERGED with dh1/dz1 (independent)
    mgemm_dual<<<1088, gB, 0, stream>>>(
        ga(h1T, dz2T, nullptr, nullptr, nullptr, nullptr, gWp + DD * DD, nullptr, nullptr, 0, 0, nullptr,
           DD, DD, RROWS, RROWS, 2 * DD * DD, 0),
        ga(dz2, WT(9), nullptr, d2, z1, nullptr, dz1, nullptr, dz1T, 0, 512, gb,
           RROWS, DD, DD, DD, DD, DD));

    // gW0 grad (split-K partials)
    mgemm<6, 64, 128, false, false><<<dim3(4, 8, SPLITK), gB, 0, stream>>>(
        ga(kT, dz1T, nullptr, nullptr, nullptr, nullptr, gWp, nullptr, nullptr, 0, 0, nullptr,
           DD, DD, RROWS, RROWS, 2 * DD * DD, 0));

    // AdamW (weights: partial-sum + update + transpose; biases in z==2 slice)
    adamw_transp<<<dim3(8, 8, 3), 256, 0, stream>>>(lmmW, gWp, WT(10), lmmb, gb, bn);

    // retrieval with updated memory
    mgemm<1, 64, 64, false, false><<<dim3(8, 68), gB, 0, stream>>>(
        ga(qkv, WT(10), bn, qkv, nullptr, nullptr, h1r, nullptr, nullptr, 0, 0, nullptr,
           RROWS, DD, DD, 1536, 1536, 0));
    mgemm<1, 64, 64, false, false><<<dim3(8, 68), gB, 0, stream>>>(
        ga(h1r, WT(11), bn + DD, h1r, nullptr, nullptr, retr, nullptr, nullptr, 0, 0, nullptr,
           RROWS, DD, DD, DD, DD, 0));

    // fused SWA projections, MFMA attention, out-proj
    mgemm<0, 64, 128, false, false><<<dim3(12, 68), gB, 0, stream>>>(
        ga(retr, WT(5), cbS, nullptr, nullptr, nullptr, qkv, nullptr, nullptr, 0, 0, nullptr,
           RROWS, 1536, DD, DD, 0, 0));
    swa_mfma<<<dim3(16, 8, 4), 256, 0, stream>>>(qkv, o);
    mgemm<5, 64, 64, false, false><<<dim3(8, 64), gB, 0, stream>>>(
        ga(o, WT(8), swab + 3 * DD, nullptr, nullptr, nullptr, out, nullptr, nullptr, 0, 0, nullptr,
           OROWS, DD, DD, DD, 0, 0));
}